// Round 2
// baseline (5245.637 us; speedup 1.0000x reference)
//
#include <hip/hip_runtime.h>
#include <math.h>

namespace {
constexpr int N_   = 10000;
constexpr int E_   = 80000;
constexpr int ORI_ = 12;
constexpr int HC_  = 768;   // ORI*C
constexpr float EPS_ = 1e-6f;
}

__device__ __forceinline__ float gelu_f(float x) {
  return 0.5f * x * (1.0f + tanhf(0.7978845608028654f * (x + 0.044715f * x * x * x)));
}

// wave-private LDS exchange fence: commit my wave's ds_writes, stop compiler reordering
__device__ __forceinline__ void wave_sync() {
  asm volatile("s_waitcnt lgkmcnt(0)" ::: "memory");
  __builtin_amdgcn_wave_barrier();
}

__device__ __forceinline__ float wave_sum64(float v) {
#pragma unroll
  for (int off = 32; off > 0; off >>= 1) v += __shfl_xor(v, off, 64);
  return v;
}

// ---------------------------------------------------------------------------
// Setup: ori_grid (12x3) + fk[i][p][o][c] = sum_b fkb[p,o,b]*fib_kw[i][b,c]
// ---------------------------------------------------------------------------
__global__ __launch_bounds__(256) void k_setup(
    const float* __restrict__ fb_w1, const float* __restrict__ fb_b1,
    const float* __restrict__ fb_w2, const float* __restrict__ fb_b2,
    const float* __restrict__ fib_kw,
    float* __restrict__ g_ori, float* __restrict__ g_fk) {
  __shared__ float s_ori[36];
  __shared__ float s_scr[4][2][64];
  int tid = threadIdx.x;
  if (tid < 12) {
    const double PI = 3.14159265358979323846;
    double th = fmod(PI * (double)tid * (1.0 + sqrt(5.0)), 2.0 * PI);
    double ph = acos(1.0 - 2.0 * ((double)tid + 0.5) / 12.0);
    float sx = (float)(sin(ph) * cos(th));
    float sy = (float)(sin(ph) * sin(th));
    float sz = (float)cos(ph);
    s_ori[tid*3+0]=sx; s_ori[tid*3+1]=sy; s_ori[tid*3+2]=sz;
    g_ori[tid*3+0]=sx; g_ori[tid*3+1]=sy; g_ori[tid*3+2]=sz;
  }
  __syncthreads();
  int wid = tid >> 6, lane = tid & 63;
  for (int r = wid; r < 144; r += 4) {
    int p = r / 12, o = r % 12;
    float s = s_ori[p*3+0]*s_ori[o*3+0] + s_ori[p*3+1]*s_ori[o*3+1] + s_ori[p*3+2]*s_ori[o*3+2];
    float f1 = s, f2 = s*s, f3 = s*s*s;  // poly_features of 1-dim scalar, DEG=2
    float a1 = fb_b1[lane] + f1*fb_w1[0*64+lane] + f2*fb_w1[1*64+lane] + f3*fb_w1[2*64+lane];
    a1 = gelu_f(a1);
    s_scr[wid][0][lane] = a1; wave_sync();
    float a2 = fb_b2[lane];
    for (int j = 0; j < 64; ++j) a2 += s_scr[wid][0][j] * fb_w2[j*64+lane];
    float fbv = gelu_f(a2);
    s_scr[wid][1][lane] = fbv; wave_sync();
    for (int i = 0; i < 3; ++i) {
      float acc = 0.f;
      for (int j = 0; j < 64; ++j) acc += s_scr[wid][1][j] * fib_kw[i*4096 + j*64 + lane];
      g_fk[i*9216 + r*64 + lane] = acc;   // r = p*12+o
    }
  }
}

// ---------------------------------------------------------------------------
// Embed: h[n,o,c] = (x @ emb_w)[n,c] replicated over o
// ---------------------------------------------------------------------------
__global__ __launch_bounds__(256) void k_embed(
    const float* __restrict__ x, const float* __restrict__ emb_w,
    float* __restrict__ h) {
  __shared__ float s_w[16*64];
  int tid = threadIdx.x;
  for (int i = tid; i < 16*64; i += 256) s_w[i] = emb_w[i];
  __syncthreads();
  int wid = tid >> 6, lane = tid & 63;
  int nw = gridDim.x * 4;
  for (int n = blockIdx.x*4 + wid; n < N_; n += nw) {
    float acc = 0.f;
#pragma unroll
    for (int k = 0; k < 16; ++k) acc += x[n*16+k] * s_w[k*64+lane];
#pragma unroll
    for (int o = 0; o < ORI_; ++o) h[n*HC_ + o*64 + lane] = acc;
  }
}

// ---------------------------------------------------------------------------
// Message: per edge e, orientation o:
//   kb = gelu(gelu(poly(sp_inv) @ sb_w1+b1) @ sb_w2+b2); kbc = kb @ conv_kw[i]
//   atomicAdd(x1[e1,o,:], h[e0,o,:]*kbc)
// ---------------------------------------------------------------------------
__global__ __launch_bounds__(256) void k_msg(
    const float* __restrict__ pos, const int* __restrict__ ei,
    const float* __restrict__ sb_w1, const float* __restrict__ sb_b1,
    const float* __restrict__ sb_w2, const float* __restrict__ sb_b2,
    const float* __restrict__ ckw, const float* __restrict__ g_ori,
    const float* __restrict__ h, float* __restrict__ x1) {
  __shared__ float s_w1[14*64];
  __shared__ float s_b1[64];
  __shared__ float s_w2[64*64];
  __shared__ float s_b2[64];
  __shared__ float s_ck[64*64];
  __shared__ float s_ori[36];
  __shared__ float s_scr[4][2][64];
  int tid = threadIdx.x;
  for (int i = tid; i < 14*64; i += 256) s_w1[i] = sb_w1[i];
  for (int i = tid; i < 64*64; i += 256) { s_w2[i] = sb_w2[i]; s_ck[i] = ckw[i]; }
  if (tid < 64) { s_b1[tid] = sb_b1[tid]; s_b2[tid] = sb_b2[tid]; }
  if (tid < 36) s_ori[tid] = g_ori[tid];
  __syncthreads();
  int wid = tid >> 6, lane = tid & 63;
  int nw = gridDim.x * 4;
  const int* e0 = ei; const int* e1 = ei + E_;
  for (int e = blockIdx.x*4 + wid; e < E_; e += nw) {
    int a = e0[e], b = e1[e];
    float rx = pos[a*3+0]-pos[b*3+0];
    float ry = pos[a*3+1]-pos[b*3+1];
    float rz = pos[a*3+2]-pos[b*3+2];
    const float* hrow = h + a*HC_;
    float* xrow = x1 + b*HC_;
#pragma unroll 1
    for (int o = 0; o < ORI_; ++o) {
      float ox = s_ori[o*3+0], oy = s_ori[o*3+1], oz = s_ori[o*3+2];
      float i1 = rx*ox + ry*oy + rz*oz;
      float px = rx - i1*ox, py = ry - i1*oy, pz = rz - i1*oz;
      float i2 = sqrtf(px*px + py*py + pz*pz);
      float f[14];
      f[0]=i1; f[1]=i2; f[2]=i1*i1; f[3]=i1*i2; f[4]=i2*i1; f[5]=i2*i2;
      f[6]=f[2]*i1; f[7]=f[2]*i2; f[8]=f[3]*i1; f[9]=f[3]*i2;
      f[10]=f[4]*i1; f[11]=f[4]*i2; f[12]=f[5]*i1; f[13]=f[5]*i2;
      float a1 = s_b1[lane];
#pragma unroll
      for (int p = 0; p < 14; ++p) a1 += f[p] * s_w1[p*64+lane];
      a1 = gelu_f(a1);
      s_scr[wid][0][lane] = a1; wave_sync();
      float a2 = s_b2[lane];
      for (int j = 0; j < 64; ++j) a2 += s_scr[wid][0][j] * s_w2[j*64+lane];
      a2 = gelu_f(a2);
      s_scr[wid][1][lane] = a2; wave_sync();
      float kc = 0.f;
      for (int j = 0; j < 64; ++j) kc += s_scr[wid][1][j] * s_ck[j*64+lane];
      float m = hrow[o*64+lane] * kc;
      atomicAdd(&xrow[o*64+lane], m);
    }
  }
}

// ---------------------------------------------------------------------------
// Conv-mix + LayerNorm (in place on x1):
//   x2[n,p,c] = (1/12) sum_o x1[n,o,c]*fk[p,o,c] + conv_b[c]; then LN over c
// ---------------------------------------------------------------------------
__global__ __launch_bounds__(256) void k_convln(
    float* __restrict__ x1, const float* __restrict__ g_fk_i,
    const float* __restrict__ conv_b, const float* __restrict__ ln_s,
    const float* __restrict__ ln_b) {
  __shared__ float s_fk[9216];
  __shared__ float s_cb[64], s_ls[64], s_lb[64];
  int tid = threadIdx.x;
  for (int i = tid; i < 9216; i += 256) s_fk[i] = g_fk_i[i];
  if (tid < 64) { s_cb[tid]=conv_b[tid]; s_ls[tid]=ln_s[tid]; s_lb[tid]=ln_b[tid]; }
  __syncthreads();
  int wid = tid >> 6, lane = tid & 63;
  int nw = gridDim.x * 4;
  for (int n = blockIdx.x*4 + wid; n < N_; n += nw) {
    float xr[12];
#pragma unroll
    for (int o = 0; o < 12; ++o) xr[o] = x1[n*HC_ + o*64 + lane];
    float xo[12];
#pragma unroll
    for (int p = 0; p < 12; ++p) {
      float acc = 0.f;
#pragma unroll
      for (int o = 0; o < 12; ++o) acc += xr[o] * s_fk[(p*12+o)*64 + lane];
      acc = acc * (1.0f/12.0f) + s_cb[lane];
      float s1 = wave_sum64(acc);
      float s2 = wave_sum64(acc*acc);
      float mu = s1 * (1.0f/64.0f);
      float var = s2 * (1.0f/64.0f) - mu*mu;
      xo[p] = (acc - mu) * rsqrtf(var + EPS_) * s_ls[lane] + s_lb[lane];
    }
#pragma unroll
    for (int p = 0; p < 12; ++p) x1[n*HC_ + p*64 + lane] = xo[p];
  }
}

// ---------------------------------------------------------------------------
// Node MLP 64->256->64 + residual into h + readout accumulation into racc
// ---------------------------------------------------------------------------
__global__ __launch_bounds__(256) void k_mlp(
    const float* __restrict__ xn, float* __restrict__ h,
    const float* __restrict__ l1_w, const float* __restrict__ l1_b,
    const float* __restrict__ l2_w, const float* __restrict__ l2_b,
    const float* __restrict__ ro_w, const float* __restrict__ ro_b,
    float* __restrict__ racc) {
  __shared__ float s_w1[64*256];
  __shared__ float s_w2[256*64];
  __shared__ float s_b1[256];
  __shared__ float s_b2[64];
  __shared__ float s_ro[128];
  __shared__ float s_x[4][64];
  __shared__ float s_hm[4][256];
  int tid = threadIdx.x;
  for (int i = tid; i < 16384; i += 256) { s_w1[i] = l1_w[i]; s_w2[i] = l2_w[i]; }
  s_b1[tid] = l1_b[tid];
  if (tid < 64) s_b2[tid] = l2_b[tid];
  if (tid < 128) s_ro[tid] = ro_w[tid];
  __syncthreads();
  float rb0 = ro_b[0], rb1 = ro_b[1];
  int wid = tid >> 6, lane = tid & 63;
  int nw = gridDim.x * 4;
  for (int r = blockIdx.x*4 + wid; r < N_*ORI_; r += nw) {
    s_x[wid][lane] = xn[r*64 + lane];
    wave_sync();
    float m0 = s_b1[4*lane+0], m1 = s_b1[4*lane+1], m2 = s_b1[4*lane+2], m3 = s_b1[4*lane+3];
    for (int c = 0; c < 64; ++c) {
      float xv = s_x[wid][c];
      const float* wrow = &s_w1[c*256 + 4*lane];
      m0 += xv * wrow[0]; m1 += xv * wrow[1]; m2 += xv * wrow[2]; m3 += xv * wrow[3];
    }
    s_hm[wid][4*lane+0] = gelu_f(m0);
    s_hm[wid][4*lane+1] = gelu_f(m1);
    s_hm[wid][4*lane+2] = gelu_f(m2);
    s_hm[wid][4*lane+3] = gelu_f(m3);
    wave_sync();
    float acc = s_b2[lane];
    for (int j = 0; j < 256; ++j) acc += s_hm[wid][j] * s_w2[j*64 + lane];
    float hnew = acc + h[r*64 + lane];
    h[r*64 + lane] = hnew;
    float r0 = wave_sum64(hnew * s_ro[lane*2+0]);
    float r1 = wave_sum64(hnew * s_ro[lane*2+1]);
    if (lane == 0) {
      racc[r*2+0] += r0 + rb0;
      racc[r*2+1] += r1 + rb1;
    }
  }
}

// ---------------------------------------------------------------------------
// Final: per-node reduce racc over orientations, segment-sum into 32 outputs
// out[0..7] = out_s ; out[8 + b*3 + d] = out_v
// ---------------------------------------------------------------------------
__global__ __launch_bounds__(256) void k_final(
    const float* __restrict__ racc, const int* __restrict__ batch,
    const float* __restrict__ g_ori, float* __restrict__ out) {
  __shared__ float s_part[32];
  __shared__ float s_ori[36];
  int tid = threadIdx.x;
  if (tid < 32) s_part[tid] = 0.f;
  if (tid < 36) s_ori[tid] = g_ori[tid];
  __syncthreads();
  const float sc = 1.0f / 36.0f;  // /3 layers, /12 orientations
  for (int n = blockIdx.x*256 + tid; n < N_; n += gridDim.x*256) {
    int bt = batch[n];
    float ss = 0.f, v0 = 0.f, v1 = 0.f, v2 = 0.f;
#pragma unroll
    for (int o = 0; o < 12; ++o) {
      float r0 = racc[n*24 + o*2 + 0];
      float r1 = racc[n*24 + o*2 + 1];
      ss += r0;
      v0 += r1 * s_ori[o*3+0];
      v1 += r1 * s_ori[o*3+1];
      v2 += r1 * s_ori[o*3+2];
    }
    atomicAdd(&s_part[bt], ss*sc);
    atomicAdd(&s_part[8 + bt*3 + 0], v0*sc);
    atomicAdd(&s_part[8 + bt*3 + 1], v1*sc);
    atomicAdd(&s_part[8 + bt*3 + 2], v2*sc);
  }
  __syncthreads();
  if (tid < 32) atomicAdd(&out[tid], s_part[tid]);
}

extern "C" void kernel_launch(void* const* d_in, const int* in_sizes, int n_in,
                              void* d_out, int out_size, void* d_ws, size_t ws_size,
                              hipStream_t stream) {
  const float* pos    = (const float*)d_in[0];
  const float* x      = (const float*)d_in[1];
  const int*   ei     = (const int*)d_in[2];
  const int*   batch  = (const int*)d_in[3];
  const float* sb_w1  = (const float*)d_in[4];
  const float* sb_b1  = (const float*)d_in[5];
  const float* sb_w2  = (const float*)d_in[6];
  const float* sb_b2  = (const float*)d_in[7];
  const float* fb_w1  = (const float*)d_in[8];
  const float* fb_b1  = (const float*)d_in[9];
  const float* fb_w2  = (const float*)d_in[10];
  const float* fb_b2  = (const float*)d_in[11];
  const float* emb_w  = (const float*)d_in[12];
  const float* conv_kw= (const float*)d_in[13];
  const float* fib_kw = (const float*)d_in[14];
  const float* conv_b = (const float*)d_in[15];
  const float* ln_s   = (const float*)d_in[16];
  const float* ln_b   = (const float*)d_in[17];
  const float* l1_w   = (const float*)d_in[18];
  const float* l1_b   = (const float*)d_in[19];
  const float* l2_w   = (const float*)d_in[20];
  const float* l2_b   = (const float*)d_in[21];
  const float* ro_w   = (const float*)d_in[22];
  const float* ro_b   = (const float*)d_in[23];

  float* ws_f   = (float*)d_ws;
  float* g_ori  = ws_f;                    // 64 (12x3 used)
  float* g_fk   = ws_f + 64;               // 3*12*12*64 = 27648
  float* g_h    = ws_f + 64 + 27648;       // N*12*64 = 7,680,000
  float* g_x1   = g_h + 7680000;           // 7,680,000
  float* g_racc = g_x1 + 7680000;          // N*12*2 = 240,000
  float* out_f  = (float*)d_out;

  (void)hipMemsetAsync(g_racc, 0, 240000*sizeof(float), stream);
  k_setup<<<1, 256, 0, stream>>>(fb_w1, fb_b1, fb_w2, fb_b2, fib_kw, g_ori, g_fk);
  k_embed<<<512, 256, 0, stream>>>(x, emb_w, g_h);
  for (int i = 0; i < 3; ++i) {
    (void)hipMemsetAsync(g_x1, 0, 7680000*sizeof(float), stream);
    k_msg<<<1024, 256, 0, stream>>>(pos, ei, sb_w1, sb_b1, sb_w2, sb_b2,
                                    conv_kw + i*4096, g_ori, g_h, g_x1);
    k_convln<<<1024, 256, 0, stream>>>(g_x1, g_fk + i*9216, conv_b + i*64,
                                       ln_s + i*64, ln_b + i*64);
    k_mlp<<<256, 256, 0, stream>>>(g_x1, g_h, l1_w + i*16384, l1_b + i*256,
                                   l2_w + i*16384, l2_b + i*64,
                                   ro_w + i*128, ro_b + i*2, g_racc);
  }
  (void)hipMemsetAsync(out_f, 0, 32*sizeof(float), stream);
  k_final<<<128, 256, 0, stream>>>(g_racc, batch, g_ori, out_f);
}

// Round 3
// 3303.019 us; speedup vs baseline: 1.5881x; 1.5881x over previous
//
#include <hip/hip_runtime.h>
#include <math.h>

namespace {
constexpr int N_   = 10000;
constexpr int E_   = 80000;
constexpr int ORI_ = 12;
constexpr int HC_  = 768;   // ORI*C
constexpr float EPS_ = 1e-6f;

// workspace layout (float units)
constexpr size_t OFF_ORI  = 0;                       // 64
constexpr size_t OFF_FK   = 64;                      // 3*144*64 = 27648
constexpr size_t OFF_H    = OFF_FK + 27648;          // 7,680,000
constexpr size_t OFF_XN   = OFF_H + 7680000;         // 7,680,000
constexpr size_t OFF_RACC = OFF_XN + 7680000;        // 240,000
constexpr size_t OFF_RP   = OFF_RACC + 240000;       // 10001 ints
constexpr size_t OFF_CUR  = OFF_RP + 10001;          // 10001 ints
constexpr size_t OFF_E0S  = OFF_CUR + 10001;         // 80000 ints
constexpr size_t OFF_REL  = ((OFF_E0S + 80000 + 3) / 4) * 4;  // 80000 float4 (16B aligned)
constexpr size_t OFF_KB   = ((OFF_REL + 320000 + 3) / 4) * 4;
constexpr size_t NEED_FP32 = (OFF_KB + (size_t)E_ * ORI_ * 64) * 4;            // ~310 MB
constexpr size_t NEED_BF16 = OFF_KB * 4 + (size_t)E_ * ORI_ * 64 * 2;          // ~187 MB
}

__device__ __forceinline__ float gelu_f(float x) {
  float u = 0.7978845608028654f * (x + 0.044715f * x * x * x);
  float t = __expf(-2.0f * fabsf(u));              // e^{-2|u|}
  float th = __fdividef(1.0f - t, 1.0f + t);       // tanh(|u|)
  th = copysignf(th, u);
  return 0.5f * x * (1.0f + th);
}

__device__ __forceinline__ void wave_sync() {
  asm volatile("s_waitcnt lgkmcnt(0)" ::: "memory");
  __builtin_amdgcn_wave_barrier();
}

__device__ __forceinline__ float wave_sum64(float v) {
#pragma unroll
  for (int off = 32; off > 0; off >>= 1) v += __shfl_xor(v, off, 64);
  return v;
}

__device__ __forceinline__ unsigned short f2bf(float x) {
  unsigned u = __float_as_uint(x);
  unsigned r = (u + 0x7fffu + ((u >> 16) & 1u)) >> 16;  // RNE
  return (unsigned short)r;
}

// ---------------------------------------------------------------------------
// Setup: ori_grid (12x3) + fk[i][p][o][c]
// ---------------------------------------------------------------------------
__global__ __launch_bounds__(256) void k_setup(
    const float* __restrict__ fb_w1, const float* __restrict__ fb_b1,
    const float* __restrict__ fb_w2, const float* __restrict__ fb_b2,
    const float* __restrict__ fib_kw,
    float* __restrict__ g_ori, float* __restrict__ g_fk) {
  __shared__ float s_ori[36];
  __shared__ float s_scr[4][2][64];
  int tid = threadIdx.x;
  if (tid < 12) {
    const double PI = 3.14159265358979323846;
    double th = fmod(PI * (double)tid * (1.0 + sqrt(5.0)), 2.0 * PI);
    double ph = acos(1.0 - 2.0 * ((double)tid + 0.5) / 12.0);
    float sx = (float)(sin(ph) * cos(th));
    float sy = (float)(sin(ph) * sin(th));
    float sz = (float)cos(ph);
    s_ori[tid*3+0]=sx; s_ori[tid*3+1]=sy; s_ori[tid*3+2]=sz;
    g_ori[tid*3+0]=sx; g_ori[tid*3+1]=sy; g_ori[tid*3+2]=sz;
  }
  __syncthreads();
  int wid = tid >> 6, lane = tid & 63;
  for (int r = wid; r < 144; r += 4) {
    int p = r / 12, o = r % 12;
    float s = s_ori[p*3+0]*s_ori[o*3+0] + s_ori[p*3+1]*s_ori[o*3+1] + s_ori[p*3+2]*s_ori[o*3+2];
    float f1 = s, f2 = s*s, f3 = s*s*s;
    float a1 = fb_b1[lane] + f1*fb_w1[0*64+lane] + f2*fb_w1[1*64+lane] + f3*fb_w1[2*64+lane];
    a1 = gelu_f(a1);
    s_scr[wid][0][lane] = a1; wave_sync();
    float a2 = fb_b2[lane];
    for (int j = 0; j < 64; ++j) a2 += s_scr[wid][0][j] * fb_w2[j*64+lane];
    float fbv = gelu_f(a2);
    s_scr[wid][1][lane] = fbv; wave_sync();
    for (int i = 0; i < 3; ++i) {
      float acc = 0.f;
      for (int j = 0; j < 64; ++j) acc += s_scr[wid][1][j] * fib_kw[i*4096 + j*64 + lane];
      g_fk[i*9216 + r*64 + lane] = acc;
    }
  }
}

// ---------------------------------------------------------------------------
// Embed
// ---------------------------------------------------------------------------
__global__ __launch_bounds__(256) void k_embed(
    const float* __restrict__ x, const float* __restrict__ emb_w,
    float* __restrict__ h) {
  __shared__ float s_w[16*64];
  int tid = threadIdx.x;
  for (int i = tid; i < 16*64; i += 256) s_w[i] = emb_w[i];
  __syncthreads();
  int wid = tid >> 6, lane = tid & 63;
  int nw = gridDim.x * 4;
  for (int n = blockIdx.x*4 + wid; n < N_; n += nw) {
    float acc = 0.f;
#pragma unroll
    for (int k = 0; k < 16; ++k) acc += x[n*16+k] * s_w[k*64+lane];
#pragma unroll
    for (int o = 0; o < ORI_; ++o) h[n*HC_ + o*64 + lane] = acc;
  }
}

// ---------------------------------------------------------------------------
// CSR build
// ---------------------------------------------------------------------------
__global__ __launch_bounds__(256) void k_count(const int* __restrict__ ei, int* __restrict__ cnt) {
  int e = blockIdx.x*256 + threadIdx.x;
  if (e < E_) atomicAdd(&cnt[ei[E_ + e]], 1);
}

__global__ __launch_bounds__(256) void k_scan(int* __restrict__ cnt, int* __restrict__ row_ptr) {
  __shared__ int s_sum[256];
  int tid = threadIdx.x;
  int start = tid * 40, end = min(start + 40, N_);
  int s = 0;
  for (int i = start; i < end; ++i) s += cnt[i];
  s_sum[tid] = s;
  __syncthreads();
  if (tid == 0) {
    int run = 0;
    for (int i = 0; i < 256; ++i) { int t = s_sum[i]; s_sum[i] = run; run += t; }
  }
  __syncthreads();
  int run = s_sum[tid];
  for (int i = start; i < end; ++i) { int c = cnt[i]; row_ptr[i] = run; cnt[i] = run; run += c; }
  if (tid == 0) row_ptr[N_] = E_;
}

__global__ __launch_bounds__(256) void k_scatter(
    const float* __restrict__ pos, const int* __restrict__ ei,
    int* __restrict__ cursor, int* __restrict__ e0s, float4* __restrict__ rel4) {
  int e = blockIdx.x*256 + threadIdx.x;
  if (e >= E_) return;
  int a = ei[e], b = ei[E_ + e];
  int slot = atomicAdd(&cursor[b], 1);
  float rx = pos[a*3+0]-pos[b*3+0];
  float ry = pos[a*3+1]-pos[b*3+1];
  float rz = pos[a*3+2]-pos[b*3+2];
  e0s[slot] = a;
  rel4[slot] = make_float4(rx, ry, rz, __int_as_float(e));
}

// deterministic order within each bin: insertion sort by original edge id
__global__ __launch_bounds__(256) void k_sortbins(
    const int* __restrict__ row_ptr, int* __restrict__ e0s, float4* __restrict__ rel4) {
  int n = blockIdx.x*256 + threadIdx.x;
  if (n >= N_) return;
  int lo = row_ptr[n], hi = row_ptr[n+1];
  for (int i = lo + 1; i < hi; ++i) {
    float4 key = rel4[i]; int kk = __float_as_int(key.w); int ke = e0s[i];
    int j = i - 1;
    while (j >= lo && __float_as_int(rel4[j].w) > kk) {
      rel4[j+1] = rel4[j]; e0s[j+1] = e0s[j]; --j;
    }
    rel4[j+1] = key; e0s[j+1] = ke;
  }
}

// ---------------------------------------------------------------------------
// Basis: per (edge-slot, ori) row, lane-per-row MLP -> kb[s][o][c] (once!)
// ---------------------------------------------------------------------------
template<int BF16>
__global__ __launch_bounds__(256) void k_basis(
    const float4* __restrict__ rel4,
    const float* __restrict__ sb_w1, const float* __restrict__ sb_b1,
    const float* __restrict__ sb_w2, const float* __restrict__ sb_b2,
    const float* __restrict__ g_ori, void* __restrict__ kb_out) {
  __shared__ float s_w1[14*64];
  __shared__ float s_w2[64*64];
  __shared__ float s_b1[64];
  __shared__ float s_b2[64];
  __shared__ float s_ori[36];
  int tid = threadIdx.x;
  for (int i = tid; i < 14*64; i += 256) s_w1[i] = sb_w1[i];
  for (int i = tid; i < 64*64; i += 256) s_w2[i] = sb_w2[i];
  if (tid < 64) { s_b1[tid] = sb_b1[tid]; s_b2[tid] = sb_b2[tid]; }
  if (tid < 36) s_ori[tid] = g_ori[tid];
  __syncthreads();
  int r = blockIdx.x*256 + tid;
  if (r >= E_*ORI_) return;
  int s = r / 12, o = r - s*12;
  float4 rv = rel4[s];
  float rx = rv.x, ry = rv.y, rz = rv.z;
  float ox = s_ori[o*3+0], oy = s_ori[o*3+1], oz = s_ori[o*3+2];
  float i1 = rx*ox + ry*oy + rz*oz;
  float px = rx - i1*ox, py = ry - i1*oy, pz = rz - i1*oz;
  float i2 = sqrtf(px*px + py*py + pz*pz);
  float f[14];
  f[0]=i1; f[1]=i2; f[2]=i1*i1; f[3]=i1*i2; f[4]=i2*i1; f[5]=i2*i2;
  f[6]=f[2]*i1; f[7]=f[2]*i2; f[8]=f[3]*i1; f[9]=f[3]*i2;
  f[10]=f[4]*i1; f[11]=f[4]*i2; f[12]=f[5]*i1; f[13]=f[5]*i2;
  float h1[64];
#pragma unroll
  for (int j4 = 0; j4 < 16; ++j4) {
    float4 a = *(const float4*)&s_b1[j4*4];
#pragma unroll
    for (int p = 0; p < 14; ++p) {
      float4 w = *(const float4*)&s_w1[p*64 + j4*4];
      a.x += f[p]*w.x; a.y += f[p]*w.y; a.z += f[p]*w.z; a.w += f[p]*w.w;
    }
    h1[j4*4+0] = gelu_f(a.x); h1[j4*4+1] = gelu_f(a.y);
    h1[j4*4+2] = gelu_f(a.z); h1[j4*4+3] = gelu_f(a.w);
  }
#pragma unroll 1
  for (int c4 = 0; c4 < 16; ++c4) {
    float4 a = *(const float4*)&s_b2[c4*4];
#pragma unroll
    for (int j = 0; j < 64; ++j) {
      float4 w = *(const float4*)&s_w2[j*64 + c4*4];
      float hv = h1[j];
      a.x += hv*w.x; a.y += hv*w.y; a.z += hv*w.z; a.w += hv*w.w;
    }
    a.x = gelu_f(a.x); a.y = gelu_f(a.y); a.z = gelu_f(a.z); a.w = gelu_f(a.w);
    if (BF16) {
      ushort4 u; u.x=f2bf(a.x); u.y=f2bf(a.y); u.z=f2bf(a.z); u.w=f2bf(a.w);
      *(ushort4*)((unsigned short*)kb_out + (size_t)r*64 + c4*4) = u;
    } else {
      *(float4*)((float*)kb_out + (size_t)r*64 + c4*4) = a;
    }
  }
}

// ---------------------------------------------------------------------------
// Fused aggregation (CSR, no atomics) + conv-mix + LayerNorm.  Block = node.
//   ck column in VGPRs; kb row broadcast via scalar loads (readfirstlane).
// ---------------------------------------------------------------------------
template<int BF16>
__global__ __launch_bounds__(256) void k_aggr(
    const void* __restrict__ kb, const int* __restrict__ row_ptr,
    const int* __restrict__ e0s, const float* __restrict__ ck,
    const float* __restrict__ g_fk_i, const float* __restrict__ conv_b,
    const float* __restrict__ ln_s, const float* __restrict__ ln_b,
    const float* __restrict__ h, float* __restrict__ xn) {
  __shared__ float s_fk[9216];
  __shared__ float s_x1[768];
  __shared__ float s_cb[64], s_ls[64], s_lb[64];
  int tid = threadIdx.x;
  int wid = tid >> 6, lane = tid & 63;
  for (int i = tid; i < 9216; i += 256) s_fk[i] = g_fk_i[i];
  if (tid < 64) { s_cb[tid]=conv_b[tid]; s_ls[tid]=ln_s[tid]; s_lb[tid]=ln_b[tid]; }
  float ckreg[64];
#pragma unroll
  for (int j = 0; j < 64; ++j) ckreg[j] = ck[j*64 + lane];
  __syncthreads();
  int n = blockIdx.x;
  int lo = row_ptr[n], hi = row_ptr[n+1];
  for (int o = wid; o < 12; o += 4) {
    float acc = 0.f;
    for (int s = lo; s < hi; ++s) {
      int off = __builtin_amdgcn_readfirstlane(s*HC_ + o*64);
      float kc = 0.f;
      if (BF16) {
        const unsigned* rowu = (const unsigned*)((const unsigned short*)kb + off);
#pragma unroll
        for (int j2 = 0; j2 < 32; ++j2) {
          unsigned w = rowu[j2];
          kc += __uint_as_float(w << 16) * ckreg[2*j2]
              + __uint_as_float(w & 0xffff0000u) * ckreg[2*j2+1];
        }
      } else {
        const float* rowf = (const float*)kb + off;
#pragma unroll
        for (int j = 0; j < 64; ++j) kc += rowf[j] * ckreg[j];
      }
      int e0v = e0s[s];
      acc += h[(size_t)e0v*HC_ + o*64 + lane] * kc;
    }
    s_x1[o*64 + lane] = acc;
  }
  __syncthreads();
  for (int p = wid; p < 12; p += 4) {
    float a = 0.f;
#pragma unroll
    for (int o = 0; o < 12; ++o) a += s_x1[o*64+lane] * s_fk[(p*12+o)*64 + lane];
    a = a * (1.0f/12.0f) + s_cb[lane];
    float s1 = wave_sum64(a);
    float s2 = wave_sum64(a*a);
    float mu = s1 * (1.0f/64.0f);
    float var = s2 * (1.0f/64.0f) - mu*mu;
    xn[(size_t)n*HC_ + p*64 + lane] = (a - mu) * rsqrtf(var + EPS_) * s_ls[lane] + s_lb[lane];
  }
}

// ---------------------------------------------------------------------------
// Legacy (small-ws fallback): fused per-edge basis + atomic scatter
// ---------------------------------------------------------------------------
__global__ __launch_bounds__(256) void k_msg(
    const float* __restrict__ pos, const int* __restrict__ ei,
    const float* __restrict__ sb_w1, const float* __restrict__ sb_b1,
    const float* __restrict__ sb_w2, const float* __restrict__ sb_b2,
    const float* __restrict__ ckw, const float* __restrict__ g_ori,
    const float* __restrict__ h, float* __restrict__ x1) {
  __shared__ float s_w1[14*64];
  __shared__ float s_b1[64];
  __shared__ float s_w2[64*64];
  __shared__ float s_b2[64];
  __shared__ float s_ck[64*64];
  __shared__ float s_ori[36];
  __shared__ float s_scr[4][2][64];
  int tid = threadIdx.x;
  for (int i = tid; i < 14*64; i += 256) s_w1[i] = sb_w1[i];
  for (int i = tid; i < 64*64; i += 256) { s_w2[i] = sb_w2[i]; s_ck[i] = ckw[i]; }
  if (tid < 64) { s_b1[tid] = sb_b1[tid]; s_b2[tid] = sb_b2[tid]; }
  if (tid < 36) s_ori[tid] = g_ori[tid];
  __syncthreads();
  int wid = tid >> 6, lane = tid & 63;
  int nw = gridDim.x * 4;
  const int* e0 = ei; const int* e1 = ei + E_;
  for (int e = blockIdx.x*4 + wid; e < E_; e += nw) {
    int a = e0[e], b = e1[e];
    float rx = pos[a*3+0]-pos[b*3+0];
    float ry = pos[a*3+1]-pos[b*3+1];
    float rz = pos[a*3+2]-pos[b*3+2];
    const float* hrow = h + a*HC_;
    float* xrow = x1 + b*HC_;
#pragma unroll 1
    for (int o = 0; o < ORI_; ++o) {
      float ox = s_ori[o*3+0], oy = s_ori[o*3+1], oz = s_ori[o*3+2];
      float i1 = rx*ox + ry*oy + rz*oz;
      float px = rx - i1*ox, py = ry - i1*oy, pz = rz - i1*oz;
      float i2 = sqrtf(px*px + py*py + pz*pz);
      float f[14];
      f[0]=i1; f[1]=i2; f[2]=i1*i1; f[3]=i1*i2; f[4]=i2*i1; f[5]=i2*i2;
      f[6]=f[2]*i1; f[7]=f[2]*i2; f[8]=f[3]*i1; f[9]=f[3]*i2;
      f[10]=f[4]*i1; f[11]=f[4]*i2; f[12]=f[5]*i1; f[13]=f[5]*i2;
      float a1 = s_b1[lane];
#pragma unroll
      for (int p = 0; p < 14; ++p) a1 += f[p] * s_w1[p*64+lane];
      a1 = gelu_f(a1);
      s_scr[wid][0][lane] = a1; wave_sync();
      float a2 = s_b2[lane];
      for (int j = 0; j < 64; ++j) a2 += s_scr[wid][0][j] * s_w2[j*64+lane];
      a2 = gelu_f(a2);
      s_scr[wid][1][lane] = a2; wave_sync();
      float kc = 0.f;
      for (int j = 0; j < 64; ++j) kc += s_scr[wid][1][j] * s_ck[j*64+lane];
      float m = hrow[o*64+lane] * kc;
      atomicAdd(&xrow[o*64+lane], m);
    }
  }
}

__global__ __launch_bounds__(256) void k_convln(
    float* __restrict__ x1, const float* __restrict__ g_fk_i,
    const float* __restrict__ conv_b, const float* __restrict__ ln_s,
    const float* __restrict__ ln_b) {
  __shared__ float s_fk[9216];
  __shared__ float s_cb[64], s_ls[64], s_lb[64];
  int tid = threadIdx.x;
  for (int i = tid; i < 9216; i += 256) s_fk[i] = g_fk_i[i];
  if (tid < 64) { s_cb[tid]=conv_b[tid]; s_ls[tid]=ln_s[tid]; s_lb[tid]=ln_b[tid]; }
  __syncthreads();
  int wid = tid >> 6, lane = tid & 63;
  int nw = gridDim.x * 4;
  for (int n = blockIdx.x*4 + wid; n < N_; n += nw) {
    float xr[12];
#pragma unroll
    for (int o = 0; o < 12; ++o) xr[o] = x1[n*HC_ + o*64 + lane];
    float xo[12];
#pragma unroll
    for (int p = 0; p < 12; ++p) {
      float acc = 0.f;
#pragma unroll
      for (int o = 0; o < 12; ++o) acc += xr[o] * s_fk[(p*12+o)*64 + lane];
      acc = acc * (1.0f/12.0f) + s_cb[lane];
      float s1 = wave_sum64(acc);
      float s2 = wave_sum64(acc*acc);
      float mu = s1 * (1.0f/64.0f);
      float var = s2 * (1.0f/64.0f) - mu*mu;
      xo[p] = (acc - mu) * rsqrtf(var + EPS_) * s_ls[lane] + s_lb[lane];
    }
#pragma unroll
    for (int p = 0; p < 12; ++p) x1[n*HC_ + p*64 + lane] = xo[p];
  }
}

// ---------------------------------------------------------------------------
// Node MLP 64->256->64 + residual + readout accumulation
// ---------------------------------------------------------------------------
__global__ __launch_bounds__(256) void k_mlp(
    const float* __restrict__ xn, float* __restrict__ h,
    const float* __restrict__ l1_w, const float* __restrict__ l1_b,
    const float* __restrict__ l2_w, const float* __restrict__ l2_b,
    const float* __restrict__ ro_w, const float* __restrict__ ro_b,
    float* __restrict__ racc) {
  __shared__ float s_w1[64*256];
  __shared__ float s_w2[256*64];
  __shared__ float s_b1[256];
  __shared__ float s_b2[64];
  __shared__ float s_ro[128];
  __shared__ float s_x[4][64];
  __shared__ float s_hm[4][256];
  int tid = threadIdx.x;
  for (int i = tid; i < 16384; i += 256) { s_w1[i] = l1_w[i]; s_w2[i] = l2_w[i]; }
  s_b1[tid] = l1_b[tid];
  if (tid < 64) s_b2[tid] = l2_b[tid];
  if (tid < 128) s_ro[tid] = ro_w[tid];
  __syncthreads();
  float rb0 = ro_b[0], rb1 = ro_b[1];
  int wid = tid >> 6, lane = tid & 63;
  int nw = gridDim.x * 4;
  for (int r = blockIdx.x*4 + wid; r < N_*ORI_; r += nw) {
    s_x[wid][lane] = xn[r*64 + lane];
    wave_sync();
    float m0 = s_b1[4*lane+0], m1 = s_b1[4*lane+1], m2 = s_b1[4*lane+2], m3 = s_b1[4*lane+3];
    for (int c = 0; c < 64; ++c) {
      float xv = s_x[wid][c];
      const float* wrow = &s_w1[c*256 + 4*lane];
      m0 += xv * wrow[0]; m1 += xv * wrow[1]; m2 += xv * wrow[2]; m3 += xv * wrow[3];
    }
    s_hm[wid][4*lane+0] = gelu_f(m0);
    s_hm[wid][4*lane+1] = gelu_f(m1);
    s_hm[wid][4*lane+2] = gelu_f(m2);
    s_hm[wid][4*lane+3] = gelu_f(m3);
    wave_sync();
    float acc = s_b2[lane];
    for (int j = 0; j < 256; ++j) acc += s_hm[wid][j] * s_w2[j*64 + lane];
    float hnew = acc + h[r*64 + lane];
    h[r*64 + lane] = hnew;
    float r0 = wave_sum64(hnew * s_ro[lane*2+0]);
    float r1 = wave_sum64(hnew * s_ro[lane*2+1]);
    if (lane == 0) {
      racc[r*2+0] += r0 + rb0;
      racc[r*2+1] += r1 + rb1;
    }
  }
}

// ---------------------------------------------------------------------------
// Final segment-sum
// ---------------------------------------------------------------------------
__global__ __launch_bounds__(256) void k_final(
    const float* __restrict__ racc, const int* __restrict__ batch,
    const float* __restrict__ g_ori, float* __restrict__ out) {
  __shared__ float s_part[32];
  __shared__ float s_ori[36];
  int tid = threadIdx.x;
  if (tid < 32) s_part[tid] = 0.f;
  if (tid < 36) s_ori[tid] = g_ori[tid];
  __syncthreads();
  const float sc = 1.0f / 36.0f;
  for (int n = blockIdx.x*256 + tid; n < N_; n += gridDim.x*256) {
    int bt = batch[n];
    float ss = 0.f, v0 = 0.f, v1 = 0.f, v2 = 0.f;
#pragma unroll
    for (int o = 0; o < 12; ++o) {
      float r0 = racc[n*24 + o*2 + 0];
      float r1 = racc[n*24 + o*2 + 1];
      ss += r0;
      v0 += r1 * s_ori[o*3+0];
      v1 += r1 * s_ori[o*3+1];
      v2 += r1 * s_ori[o*3+2];
    }
    atomicAdd(&s_part[bt], ss*sc);
    atomicAdd(&s_part[8 + bt*3 + 0], v0*sc);
    atomicAdd(&s_part[8 + bt*3 + 1], v1*sc);
    atomicAdd(&s_part[8 + bt*3 + 2], v2*sc);
  }
  __syncthreads();
  if (tid < 32) atomicAdd(&out[tid], s_part[tid]);
}

extern "C" void kernel_launch(void* const* d_in, const int* in_sizes, int n_in,
                              void* d_out, int out_size, void* d_ws, size_t ws_size,
                              hipStream_t stream) {
  const float* pos    = (const float*)d_in[0];
  const float* x      = (const float*)d_in[1];
  const int*   ei     = (const int*)d_in[2];
  const int*   batch  = (const int*)d_in[3];
  const float* sb_w1  = (const float*)d_in[4];
  const float* sb_b1  = (const float*)d_in[5];
  const float* sb_w2  = (const float*)d_in[6];
  const float* sb_b2  = (const float*)d_in[7];
  const float* fb_w1  = (const float*)d_in[8];
  const float* fb_b1  = (const float*)d_in[9];
  const float* fb_w2  = (const float*)d_in[10];
  const float* fb_b2  = (const float*)d_in[11];
  const float* emb_w  = (const float*)d_in[12];
  const float* conv_kw= (const float*)d_in[13];
  const float* fib_kw = (const float*)d_in[14];
  const float* conv_b = (const float*)d_in[15];
  const float* ln_s   = (const float*)d_in[16];
  const float* ln_b   = (const float*)d_in[17];
  const float* l1_w   = (const float*)d_in[18];
  const float* l1_b   = (const float*)d_in[19];
  const float* l2_w   = (const float*)d_in[20];
  const float* l2_b   = (const float*)d_in[21];
  const float* ro_w   = (const float*)d_in[22];
  const float* ro_b   = (const float*)d_in[23];

  float* ws_f   = (float*)d_ws;
  float* g_ori  = ws_f + OFF_ORI;
  float* g_fk   = ws_f + OFF_FK;
  float* g_h    = ws_f + OFF_H;
  float* g_xn   = ws_f + OFF_XN;     // xn buffer (legacy: x1 buffer)
  float* g_racc = ws_f + OFF_RACC;
  int*   row_ptr= (int*)(ws_f + OFF_RP);
  int*   cursor = (int*)(ws_f + OFF_CUR);
  int*   e0s    = (int*)(ws_f + OFF_E0S);
  float4* rel4  = (float4*)(ws_f + OFF_REL);
  void*  kb     = (void*)(ws_f + OFF_KB);
  float* out_f  = (float*)d_out;

  int mode = (ws_size >= NEED_FP32) ? 0 : (ws_size >= NEED_BF16 ? 1 : 2);

  (void)hipMemsetAsync(g_racc, 0, 240000*sizeof(float), stream);
  k_setup<<<1, 256, 0, stream>>>(fb_w1, fb_b1, fb_w2, fb_b2, fib_kw, g_ori, g_fk);
  k_embed<<<512, 256, 0, stream>>>(x, emb_w, g_h);

  if (mode < 2) {
    (void)hipMemsetAsync(cursor, 0, (N_+1)*sizeof(int), stream);
    k_count<<<(E_+255)/256, 256, 0, stream>>>(ei, cursor);
    k_scan<<<1, 256, 0, stream>>>(cursor, row_ptr);
    k_scatter<<<(E_+255)/256, 256, 0, stream>>>(pos, ei, cursor, e0s, rel4);
    k_sortbins<<<(N_+255)/256, 256, 0, stream>>>(row_ptr, e0s, rel4);
    if (mode == 0)
      k_basis<0><<<(E_*ORI_)/256, 256, 0, stream>>>(rel4, sb_w1, sb_b1, sb_w2, sb_b2, g_ori, kb);
    else
      k_basis<1><<<(E_*ORI_)/256, 256, 0, stream>>>(rel4, sb_w1, sb_b1, sb_w2, sb_b2, g_ori, kb);
    for (int i = 0; i < 3; ++i) {
      if (mode == 0)
        k_aggr<0><<<N_, 256, 0, stream>>>(kb, row_ptr, e0s, conv_kw + i*4096,
                                          g_fk + i*9216, conv_b + i*64,
                                          ln_s + i*64, ln_b + i*64, g_h, g_xn);
      else
        k_aggr<1><<<N_, 256, 0, stream>>>(kb, row_ptr, e0s, conv_kw + i*4096,
                                          g_fk + i*9216, conv_b + i*64,
                                          ln_s + i*64, ln_b + i*64, g_h, g_xn);
      k_mlp<<<256, 256, 0, stream>>>(g_xn, g_h, l1_w + i*16384, l1_b + i*256,
                                     l2_w + i*16384, l2_b + i*64,
                                     ro_w + i*128, ro_b + i*2, g_racc);
    }
  } else {
    for (int i = 0; i < 3; ++i) {
      (void)hipMemsetAsync(g_xn, 0, 7680000*sizeof(float), stream);
      k_msg<<<1024, 256, 0, stream>>>(pos, ei, sb_w1, sb_b1, sb_w2, sb_b2,
                                      conv_kw + i*4096, g_ori, g_h, g_xn);
      k_convln<<<1024, 256, 0, stream>>>(g_xn, g_fk + i*9216, conv_b + i*64,
                                         ln_s + i*64, ln_b + i*64);
      k_mlp<<<256, 256, 0, stream>>>(g_xn, g_h, l1_w + i*16384, l1_b + i*256,
                                     l2_w + i*16384, l2_b + i*64,
                                     ro_w + i*128, ro_b + i*2, g_racc);
    }
  }
  (void)hipMemsetAsync(out_f, 0, 32*sizeof(float), stream);
  k_final<<<128, 256, 0, stream>>>(g_racc, batch, g_ori, out_f);
}

// Round 4
// 2206.562 us; speedup vs baseline: 2.3773x; 1.4969x over previous
//
#include <hip/hip_runtime.h>
#include <math.h>

namespace {
constexpr int N_   = 10000;
constexpr int E_   = 80000;
constexpr int ORI_ = 12;
constexpr int HC_  = 768;   // ORI*C
constexpr float EPS_ = 1e-6f;

// workspace layout (float units)
constexpr size_t OFF_ORI  = 0;                       // 64
constexpr size_t OFF_FK   = 64;                      // 3*144*64 = 27648
constexpr size_t OFF_H    = OFF_FK + 27648;          // 7,680,000
constexpr size_t OFF_XN   = OFF_H + 7680000;         // 7,680,000
constexpr size_t OFF_RACC = OFF_XN + 7680000;        // 240,000
constexpr size_t OFF_RP   = OFF_RACC + 240000;       // 10001 ints
constexpr size_t OFF_CUR  = OFF_RP + 10001;          // 10001 ints
constexpr size_t OFF_E0S  = OFF_CUR + 10001;         // 80000 ints
constexpr size_t OFF_REL  = ((OFF_E0S + 80000 + 3) / 4) * 4;  // 80000 float4 (16B aligned)
constexpr size_t OFF_KB   = ((OFF_REL + 320000 + 3) / 4) * 4;
constexpr size_t NEED_FP32 = (OFF_KB + (size_t)E_ * ORI_ * 64) * 4;            // ~310 MB
constexpr size_t NEED_BF16 = OFF_KB * 4 + (size_t)E_ * ORI_ * 64 * 2;          // ~187 MB
}

__device__ __forceinline__ float gelu_f(float x) {
  float u = 0.7978845608028654f * (x + 0.044715f * x * x * x);
  float t = __expf(-2.0f * fabsf(u));              // e^{-2|u|}
  float th = __fdividef(1.0f - t, 1.0f + t);       // tanh(|u|)
  th = copysignf(th, u);
  return 0.5f * x * (1.0f + th);
}

__device__ __forceinline__ void wave_sync() {
  asm volatile("s_waitcnt lgkmcnt(0)" ::: "memory");
  __builtin_amdgcn_wave_barrier();
}

__device__ __forceinline__ float wave_sum64(float v) {
#pragma unroll
  for (int off = 32; off > 0; off >>= 1) v += __shfl_xor(v, off, 64);
  return v;
}

__device__ __forceinline__ unsigned short f2bf(float x) {
  unsigned u = __float_as_uint(x);
  unsigned r = (u + 0x7fffu + ((u >> 16) & 1u)) >> 16;  // RNE
  return (unsigned short)r;
}

// ---------------------------------------------------------------------------
// Setup: grid=3 (one block per layer). All weights staged in LDS first so the
// tiny MLP chain is never latency-exposed on global memory.
// ---------------------------------------------------------------------------
__global__ __launch_bounds__(256) void k_setup(
    const float* __restrict__ fb_w1, const float* __restrict__ fb_b1,
    const float* __restrict__ fb_w2, const float* __restrict__ fb_b2,
    const float* __restrict__ fib_kw,
    float* __restrict__ g_ori, float* __restrict__ g_fk) {
  __shared__ float s_ori[36];
  __shared__ float s_w1[192];
  __shared__ float s_b1[64], s_b2[64];
  __shared__ float s_w2[4096];
  __shared__ float s_fib[4096];
  __shared__ float s_h1[144*64];
  __shared__ float s_kb[144*64];
  int tid = threadIdx.x;
  int i = blockIdx.x;
  if (tid < 12) {
    const double PI = 3.14159265358979323846;
    double th = fmod(PI * (double)tid * (1.0 + sqrt(5.0)), 2.0 * PI);
    double ph = acos(1.0 - 2.0 * ((double)tid + 0.5) / 12.0);
    float sx = (float)(sin(ph) * cos(th));
    float sy = (float)(sin(ph) * sin(th));
    float sz = (float)cos(ph);
    s_ori[tid*3+0]=sx; s_ori[tid*3+1]=sy; s_ori[tid*3+2]=sz;
    if (i == 0) { g_ori[tid*3+0]=sx; g_ori[tid*3+1]=sy; g_ori[tid*3+2]=sz; }
  }
  for (int k = tid; k < 4096; k += 256) { s_w2[k] = fb_w2[k]; s_fib[k] = fib_kw[i*4096 + k]; }
  if (tid < 192) s_w1[tid] = fb_w1[tid];
  if (tid < 64) { s_b1[tid] = fb_b1[tid]; s_b2[tid] = fb_b2[tid]; }
  __syncthreads();
  int wid = tid >> 6, lane = tid & 63;
  for (int r = wid; r < 144; r += 4) {
    int p = r / 12, o = r % 12;
    float s = s_ori[p*3+0]*s_ori[o*3+0] + s_ori[p*3+1]*s_ori[o*3+1] + s_ori[p*3+2]*s_ori[o*3+2];
    float f1 = s, f2 = s*s, f3 = s*s*s;
    float a1 = s_b1[lane] + f1*s_w1[lane] + f2*s_w1[64+lane] + f3*s_w1[128+lane];
    s_h1[r*64+lane] = gelu_f(a1);
  }
  __syncthreads();
  for (int r = wid; r < 144; r += 4) {
    float a2 = s_b2[lane];
    for (int j = 0; j < 64; ++j) a2 += s_h1[r*64+j] * s_w2[j*64+lane];
    s_kb[r*64+lane] = gelu_f(a2);
  }
  __syncthreads();
  for (int r = wid; r < 144; r += 4) {
    float acc = 0.f;
    for (int j = 0; j < 64; ++j) acc += s_kb[r*64+j] * s_fib[j*64+lane];
    g_fk[i*9216 + r*64 + lane] = acc;
  }
}

// ---------------------------------------------------------------------------
// Embed
// ---------------------------------------------------------------------------
__global__ __launch_bounds__(256) void k_embed(
    const float* __restrict__ x, const float* __restrict__ emb_w,
    float* __restrict__ h) {
  __shared__ float s_w[16*64];
  int tid = threadIdx.x;
  for (int i = tid; i < 16*64; i += 256) s_w[i] = emb_w[i];
  __syncthreads();
  int wid = tid >> 6, lane = tid & 63;
  int nw = gridDim.x * 4;
  for (int n = blockIdx.x*4 + wid; n < N_; n += nw) {
    float acc = 0.f;
#pragma unroll
    for (int k = 0; k < 16; ++k) acc += x[n*16+k] * s_w[k*64+lane];
#pragma unroll
    for (int o = 0; o < ORI_; ++o) h[n*HC_ + o*64 + lane] = acc;
  }
}

// ---------------------------------------------------------------------------
// CSR build
// ---------------------------------------------------------------------------
__global__ __launch_bounds__(256) void k_count(const int* __restrict__ ei, int* __restrict__ cnt) {
  int e = blockIdx.x*256 + threadIdx.x;
  if (e < E_) atomicAdd(&cnt[ei[E_ + e]], 1);
}

__global__ __launch_bounds__(256) void k_scan(int* __restrict__ cnt, int* __restrict__ row_ptr) {
  __shared__ int s_sum[256];
  int tid = threadIdx.x;
  int start = tid * 40, end = min(start + 40, N_);
  int s = 0;
  for (int i = start; i < end; ++i) s += cnt[i];
  s_sum[tid] = s;
  __syncthreads();
  if (tid == 0) {
    int run = 0;
    for (int i = 0; i < 256; ++i) { int t = s_sum[i]; s_sum[i] = run; run += t; }
  }
  __syncthreads();
  int run = s_sum[tid];
  for (int i = start; i < end; ++i) { int c = cnt[i]; row_ptr[i] = run; cnt[i] = run; run += c; }
  if (tid == 0) row_ptr[N_] = E_;
}

__global__ __launch_bounds__(256) void k_scatter(
    const float* __restrict__ pos, const int* __restrict__ ei,
    int* __restrict__ cursor, int* __restrict__ e0s, float4* __restrict__ rel4) {
  int e = blockIdx.x*256 + threadIdx.x;
  if (e >= E_) return;
  int a = ei[e], b = ei[E_ + e];
  int slot = atomicAdd(&cursor[b], 1);
  float rx = pos[a*3+0]-pos[b*3+0];
  float ry = pos[a*3+1]-pos[b*3+1];
  float rz = pos[a*3+2]-pos[b*3+2];
  e0s[slot] = a;
  rel4[slot] = make_float4(rx, ry, rz, __int_as_float(e));
}

// deterministic order within each bin: insertion sort by original edge id
__global__ __launch_bounds__(256) void k_sortbins(
    const int* __restrict__ row_ptr, int* __restrict__ e0s, float4* __restrict__ rel4) {
  int n = blockIdx.x*256 + threadIdx.x;
  if (n >= N_) return;
  int lo = row_ptr[n], hi = row_ptr[n+1];
  for (int i = lo + 1; i < hi; ++i) {
    float4 key = rel4[i]; int kk = __float_as_int(key.w); int ke = e0s[i];
    int j = i - 1;
    while (j >= lo && __float_as_int(rel4[j].w) > kk) {
      rel4[j+1] = rel4[j]; e0s[j+1] = e0s[j]; --j;
    }
    rel4[j+1] = key; e0s[j+1] = ke;
  }
}

// ---------------------------------------------------------------------------
// Basis: 2 (edge-slot,ori) rows per thread (same edge, ori o and o+1) so the
// LDS weight reads amortize over 2 rows.  kb[s][o][c].
// ---------------------------------------------------------------------------
template<int BF16>
__global__ __launch_bounds__(256) void k_basis(
    const float4* __restrict__ rel4,
    const float* __restrict__ sb_w1, const float* __restrict__ sb_b1,
    const float* __restrict__ sb_w2, const float* __restrict__ sb_b2,
    const float* __restrict__ g_ori, void* __restrict__ kb_out) {
  __shared__ float s_w1[14*64];
  __shared__ float s_w2[64*64];
  __shared__ float s_b1[64];
  __shared__ float s_b2[64];
  __shared__ float s_ori[36];
  int tid = threadIdx.x;
  for (int i = tid; i < 14*64; i += 256) s_w1[i] = sb_w1[i];
  for (int i = tid; i < 64*64; i += 256) s_w2[i] = sb_w2[i];
  if (tid < 64) { s_b1[tid] = sb_b1[tid]; s_b2[tid] = sb_b2[tid]; }
  if (tid < 36) s_ori[tid] = g_ori[tid];
  __syncthreads();
  int r2 = blockIdx.x*256 + tid;
  if (r2 >= E_*ORI_/2) return;
  int r = r2 * 2;                       // even row; pair (r, r+1) share the edge
  int s = r / 12, o = r - s*12;
  float4 rv = rel4[s];
  float rx = rv.x, ry = rv.y, rz = rv.z;
  float fa[14], fb[14];
#pragma unroll
  for (int hh = 0; hh < 2; ++hh) {
    int oo = o + hh;
    float ox = s_ori[oo*3+0], oy = s_ori[oo*3+1], oz = s_ori[oo*3+2];
    float i1 = rx*ox + ry*oy + rz*oz;
    float px = rx - i1*ox, py = ry - i1*oy, pz = rz - i1*oz;
    float i2 = sqrtf(px*px + py*py + pz*pz);
    float* f = hh ? fb : fa;
    f[0]=i1; f[1]=i2; f[2]=i1*i1; f[3]=i1*i2; f[4]=i2*i1; f[5]=i2*i2;
    f[6]=f[2]*i1; f[7]=f[2]*i2; f[8]=f[3]*i1; f[9]=f[3]*i2;
    f[10]=f[4]*i1; f[11]=f[4]*i2; f[12]=f[5]*i1; f[13]=f[5]*i2;
  }
  float h1a[64], h1b[64];
#pragma unroll
  for (int j4 = 0; j4 < 16; ++j4) {
    float4 b1v = *(const float4*)&s_b1[j4*4];
    float4 aa = b1v, ab = b1v;
#pragma unroll
    for (int p = 0; p < 14; ++p) {
      float4 w = *(const float4*)&s_w1[p*64 + j4*4];
      aa.x += fa[p]*w.x; aa.y += fa[p]*w.y; aa.z += fa[p]*w.z; aa.w += fa[p]*w.w;
      ab.x += fb[p]*w.x; ab.y += fb[p]*w.y; ab.z += fb[p]*w.z; ab.w += fb[p]*w.w;
    }
    h1a[j4*4+0]=gelu_f(aa.x); h1a[j4*4+1]=gelu_f(aa.y); h1a[j4*4+2]=gelu_f(aa.z); h1a[j4*4+3]=gelu_f(aa.w);
    h1b[j4*4+0]=gelu_f(ab.x); h1b[j4*4+1]=gelu_f(ab.y); h1b[j4*4+2]=gelu_f(ab.z); h1b[j4*4+3]=gelu_f(ab.w);
  }
#pragma unroll 1
  for (int c4 = 0; c4 < 16; ++c4) {
    float4 b2v = *(const float4*)&s_b2[c4*4];
    float4 aa = b2v, ab = b2v;
#pragma unroll
    for (int j = 0; j < 64; ++j) {
      float4 w = *(const float4*)&s_w2[j*64 + c4*4];
      float ha = h1a[j], hb = h1b[j];
      aa.x += ha*w.x; aa.y += ha*w.y; aa.z += ha*w.z; aa.w += ha*w.w;
      ab.x += hb*w.x; ab.y += hb*w.y; ab.z += hb*w.z; ab.w += hb*w.w;
    }
    aa.x = gelu_f(aa.x); aa.y = gelu_f(aa.y); aa.z = gelu_f(aa.z); aa.w = gelu_f(aa.w);
    ab.x = gelu_f(ab.x); ab.y = gelu_f(ab.y); ab.z = gelu_f(ab.z); ab.w = gelu_f(ab.w);
    if (BF16) {
      ushort4 ua; ua.x=f2bf(aa.x); ua.y=f2bf(aa.y); ua.z=f2bf(aa.z); ua.w=f2bf(aa.w);
      ushort4 ub; ub.x=f2bf(ab.x); ub.y=f2bf(ab.y); ub.z=f2bf(ab.z); ub.w=f2bf(ab.w);
      *(ushort4*)((unsigned short*)kb_out + (size_t)r*64 + c4*4) = ua;
      *(ushort4*)((unsigned short*)kb_out + (size_t)(r+1)*64 + c4*4) = ub;
    } else {
      *(float4*)((float*)kb_out + (size_t)r*64 + c4*4) = aa;
      *(float4*)((float*)kb_out + (size_t)(r+1)*64 + c4*4) = ab;
    }
  }
}

// ---------------------------------------------------------------------------
// Fused aggregation (CSR, no atomics) + conv-mix + LayerNorm.  Block = node.
// ---------------------------------------------------------------------------
template<int BF16>
__global__ __launch_bounds__(256) void k_aggr(
    const void* __restrict__ kb, const int* __restrict__ row_ptr,
    const int* __restrict__ e0s, const float* __restrict__ ck,
    const float* __restrict__ g_fk_i, const float* __restrict__ conv_b,
    const float* __restrict__ ln_s, const float* __restrict__ ln_b,
    const float* __restrict__ h, float* __restrict__ xn) {
  __shared__ float s_fk[9216];
  __shared__ float s_x1[768];
  __shared__ float s_cb[64], s_ls[64], s_lb[64];
  int tid = threadIdx.x;
  int wid = tid >> 6, lane = tid & 63;
  for (int i = tid; i < 9216; i += 256) s_fk[i] = g_fk_i[i];
  if (tid < 64) { s_cb[tid]=conv_b[tid]; s_ls[tid]=ln_s[tid]; s_lb[tid]=ln_b[tid]; }
  float ckreg[64];
#pragma unroll
  for (int j = 0; j < 64; ++j) ckreg[j] = ck[j*64 + lane];
  __syncthreads();
  int n = blockIdx.x;
  int lo = row_ptr[n], hi = row_ptr[n+1];
  for (int o = wid; o < 12; o += 4) {
    float acc = 0.f;
    for (int s = lo; s < hi; ++s) {
      int off = __builtin_amdgcn_readfirstlane(s*HC_ + o*64);
      float kc = 0.f;
      if (BF16) {
        const unsigned* rowu = (const unsigned*)((const unsigned short*)kb + off);
#pragma unroll
        for (int j2 = 0; j2 < 32; ++j2) {
          unsigned w = rowu[j2];
          kc += __uint_as_float(w << 16) * ckreg[2*j2]
              + __uint_as_float(w & 0xffff0000u) * ckreg[2*j2+1];
        }
      } else {
        const float* rowf = (const float*)kb + off;
#pragma unroll
        for (int j = 0; j < 64; ++j) kc += rowf[j] * ckreg[j];
      }
      int e0v = e0s[s];
      acc += h[(size_t)e0v*HC_ + o*64 + lane] * kc;
    }
    s_x1[o*64 + lane] = acc;
  }
  __syncthreads();
  for (int p = wid; p < 12; p += 4) {
    float a = 0.f;
#pragma unroll
    for (int o = 0; o < 12; ++o) a += s_x1[o*64+lane] * s_fk[(p*12+o)*64 + lane];
    a = a * (1.0f/12.0f) + s_cb[lane];
    float s1 = wave_sum64(a);
    float s2 = wave_sum64(a*a);
    float mu = s1 * (1.0f/64.0f);
    float var = s2 * (1.0f/64.0f) - mu*mu;
    xn[(size_t)n*HC_ + p*64 + lane] = (a - mu) * rsqrtf(var + EPS_) * s_ls[lane] + s_lb[lane];
  }
}

// ---------------------------------------------------------------------------
// Legacy (small-ws fallback): fused per-edge basis + atomic scatter
// ---------------------------------------------------------------------------
__global__ __launch_bounds__(256) void k_msg(
    const float* __restrict__ pos, const int* __restrict__ ei,
    const float* __restrict__ sb_w1, const float* __restrict__ sb_b1,
    const float* __restrict__ sb_w2, const float* __restrict__ sb_b2,
    const float* __restrict__ ckw, const float* __restrict__ g_ori,
    const float* __restrict__ h, float* __restrict__ x1) {
  __shared__ float s_w1[14*64];
  __shared__ float s_b1[64];
  __shared__ float s_w2[64*64];
  __shared__ float s_b2[64];
  __shared__ float s_ck[64*64];
  __shared__ float s_ori[36];
  __shared__ float s_scr[4][2][64];
  int tid = threadIdx.x;
  for (int i = tid; i < 14*64; i += 256) s_w1[i] = sb_w1[i];
  for (int i = tid; i < 64*64; i += 256) { s_w2[i] = sb_w2[i]; s_ck[i] = ckw[i]; }
  if (tid < 64) { s_b1[tid] = sb_b1[tid]; s_b2[tid] = sb_b2[tid]; }
  if (tid < 36) s_ori[tid] = g_ori[tid];
  __syncthreads();
  int wid = tid >> 6, lane = tid & 63;
  int nw = gridDim.x * 4;
  const int* e0 = ei; const int* e1 = ei + E_;
  for (int e = blockIdx.x*4 + wid; e < E_; e += nw) {
    int a = e0[e], b = e1[e];
    float rx = pos[a*3+0]-pos[b*3+0];
    float ry = pos[a*3+1]-pos[b*3+1];
    float rz = pos[a*3+2]-pos[b*3+2];
    const float* hrow = h + a*HC_;
    float* xrow = x1 + b*HC_;
#pragma unroll 1
    for (int o = 0; o < ORI_; ++o) {
      float ox = s_ori[o*3+0], oy = s_ori[o*3+1], oz = s_ori[o*3+2];
      float i1 = rx*ox + ry*oy + rz*oz;
      float px = rx - i1*ox, py = ry - i1*oy, pz = rz - i1*oz;
      float i2 = sqrtf(px*px + py*py + pz*pz);
      float f[14];
      f[0]=i1; f[1]=i2; f[2]=i1*i1; f[3]=i1*i2; f[4]=i2*i1; f[5]=i2*i2;
      f[6]=f[2]*i1; f[7]=f[2]*i2; f[8]=f[3]*i1; f[9]=f[3]*i2;
      f[10]=f[4]*i1; f[11]=f[4]*i2; f[12]=f[5]*i1; f[13]=f[5]*i2;
      float a1 = s_b1[lane];
#pragma unroll
      for (int p = 0; p < 14; ++p) a1 += f[p] * s_w1[p*64+lane];
      a1 = gelu_f(a1);
      s_scr[wid][0][lane] = a1; wave_sync();
      float a2 = s_b2[lane];
      for (int j = 0; j < 64; ++j) a2 += s_scr[wid][0][j] * s_w2[j*64+lane];
      a2 = gelu_f(a2);
      s_scr[wid][1][lane] = a2; wave_sync();
      float kc = 0.f;
      for (int j = 0; j < 64; ++j) kc += s_scr[wid][1][j] * s_ck[j*64+lane];
      float m = hrow[o*64+lane] * kc;
      atomicAdd(&xrow[o*64+lane], m);
    }
  }
}

__global__ __launch_bounds__(256) void k_convln(
    float* __restrict__ x1, const float* __restrict__ g_fk_i,
    const float* __restrict__ conv_b, const float* __restrict__ ln_s,
    const float* __restrict__ ln_b) {
  __shared__ float s_fk[9216];
  __shared__ float s_cb[64], s_ls[64], s_lb[64];
  int tid = threadIdx.x;
  for (int i = tid; i < 9216; i += 256) s_fk[i] = g_fk_i[i];
  if (tid < 64) { s_cb[tid]=conv_b[tid]; s_ls[tid]=ln_s[tid]; s_lb[tid]=ln_b[tid]; }
  __syncthreads();
  int wid = tid >> 6, lane = tid & 63;
  int nw = gridDim.x * 4;
  for (int n = blockIdx.x*4 + wid; n < N_; n += nw) {
    float xr[12];
#pragma unroll
    for (int o = 0; o < 12; ++o) xr[o] = x1[n*HC_ + o*64 + lane];
    float xo[12];
#pragma unroll
    for (int p = 0; p < 12; ++p) {
      float acc = 0.f;
#pragma unroll
      for (int o = 0; o < 12; ++o) acc += xr[o] * s_fk[(p*12+o)*64 + lane];
      acc = acc * (1.0f/12.0f) + s_cb[lane];
      float s1 = wave_sum64(acc);
      float s2 = wave_sum64(acc*acc);
      float mu = s1 * (1.0f/64.0f);
      float var = s2 * (1.0f/64.0f) - mu*mu;
      xo[p] = (acc - mu) * rsqrtf(var + EPS_) * s_ls[lane] + s_lb[lane];
    }
#pragma unroll
    for (int p = 0; p < 12; ++p) x1[n*HC_ + p*64 + lane] = xo[p];
  }
}

// ---------------------------------------------------------------------------
// Node MLP 64->256->64 + residual + readout.  4 rows per wave (register
// blocking: each LDS weight read feeds 4 rows).  w2 stored transposed +
// XOR-swizzled so each lane streams its own output column with b128 reads.
// ---------------------------------------------------------------------------
__global__ __launch_bounds__(256) void k_mlp(
    const float* __restrict__ xn, float* __restrict__ h,
    const float* __restrict__ l1_w, const float* __restrict__ l1_b,
    const float* __restrict__ l2_w, const float* __restrict__ l2_b,
    const float* __restrict__ ro_w, const float* __restrict__ ro_b,
    float* __restrict__ racc) {
  __shared__ float s_w1[64*256];     // [c][out], out = 4*lane+q  (b128/lane)
  __shared__ float s_w2t[64*256];    // [lane][j] float4-swizzled: slot l*64+(jb^(l&7)) holds w2[4jb+q][l]
  __shared__ float s_b1[256];
  __shared__ float s_b2[64];
  __shared__ float s_ro[128];
  __shared__ float s_x[4][4][64];    // [wid][rr][c]
  __shared__ float s_hm[4][4][256];  // [wid][rr][j]
  int tid = threadIdx.x;
  for (int k = tid; k < 16384; k += 256) {
    s_w1[k] = l1_w[k];
    int j = k >> 6, l = k & 63;          // l2_w[j][l]
    int jb = j >> 2, q = j & 3;
    s_w2t[l*256 + ((jb ^ (l & 7)) << 2) + q] = l2_w[k];
  }
  s_b1[tid] = l1_b[tid];
  if (tid < 64) s_b2[tid] = l2_b[tid];
  if (tid < 128) s_ro[tid] = ro_w[tid];
  __syncthreads();
  float rb0 = ro_b[0], rb1 = ro_b[1];
  int wid = tid >> 6, lane = tid & 63;
  int lx = lane & 7;
  int nw = gridDim.x * 4;
  const float4* w2row = (const float4*)&s_w2t[lane*256];
  for (int g = blockIdx.x*4 + wid; g < N_*ORI_/4; g += nw) {
    int r0 = g * 4;
#pragma unroll
    for (int rr = 0; rr < 4; ++rr) s_x[wid][rr][lane] = xn[(size_t)(r0+rr)*64 + lane];
    wave_sync();
    // ---- stage 1: m[rr][q] = b1 + sum_c x[rr][c] * w1[c][4*lane+q]
    float4 b1v = *(const float4*)&s_b1[4*lane];
    float4 m[4] = {b1v, b1v, b1v, b1v};
#pragma unroll
    for (int c4 = 0; c4 < 16; ++c4) {
      float4 xv[4];
#pragma unroll
      for (int rr = 0; rr < 4; ++rr) xv[rr] = *(const float4*)&s_x[wid][rr][c4*4];
#pragma unroll
      for (int cc = 0; cc < 4; ++cc) {
        float4 w = *(const float4*)&s_w1[(c4*4+cc)*256 + 4*lane];
#pragma unroll
        for (int rr = 0; rr < 4; ++rr) {
          float xs = (&xv[rr].x)[cc];
          m[rr].x += xs*w.x; m[rr].y += xs*w.y; m[rr].z += xs*w.z; m[rr].w += xs*w.w;
        }
      }
    }
#pragma unroll
    for (int rr = 0; rr < 4; ++rr) {
      s_hm[wid][rr][4*lane+0] = gelu_f(m[rr].x);
      s_hm[wid][rr][4*lane+1] = gelu_f(m[rr].y);
      s_hm[wid][rr][4*lane+2] = gelu_f(m[rr].z);
      s_hm[wid][rr][4*lane+3] = gelu_f(m[rr].w);
    }
    wave_sync();
    // ---- stage 2: acc[rr] = b2 + sum_j hm[rr][j] * w2[j][lane]
    float acc[4];
#pragma unroll
    for (int rr = 0; rr < 4; ++rr) acc[rr] = s_b2[lane];
#pragma unroll 8
    for (int jb = 0; jb < 64; ++jb) {
      float4 w = w2row[jb ^ lx];           // w2[4jb+q][lane]
#pragma unroll
      for (int rr = 0; rr < 4; ++rr) {
        float4 hm4 = *(const float4*)&s_hm[wid][rr][jb*4];
        acc[rr] += hm4.x*w.x + hm4.y*w.y + hm4.z*w.z + hm4.w*w.w;
      }
    }
    // ---- residual + store + readout
#pragma unroll
    for (int rr = 0; rr < 4; ++rr) {
      size_t idx = (size_t)(r0+rr)*64 + lane;
      float hnew = acc[rr] + h[idx];
      h[idx] = hnew;
      float v0 = wave_sum64(hnew * s_ro[lane*2+0]);
      float v1 = wave_sum64(hnew * s_ro[lane*2+1]);
      if (lane == 0) {
        racc[(r0+rr)*2+0] += v0 + rb0;
        racc[(r0+rr)*2+1] += v1 + rb1;
      }
    }
  }
}

// ---------------------------------------------------------------------------
// Final segment-sum
// ---------------------------------------------------------------------------
__global__ __launch_bounds__(256) void k_final(
    const float* __restrict__ racc, const int* __restrict__ batch,
    const float* __restrict__ g_ori, float* __restrict__ out) {
  __shared__ float s_part[32];
  __shared__ float s_ori[36];
  int tid = threadIdx.x;
  if (tid < 32) s_part[tid] = 0.f;
  if (tid < 36) s_ori[tid] = g_ori[tid];
  __syncthreads();
  const float sc = 1.0f / 36.0f;
  for (int n = blockIdx.x*256 + tid; n < N_; n += gridDim.x*256) {
    int bt = batch[n];
    float ss = 0.f, v0 = 0.f, v1 = 0.f, v2 = 0.f;
#pragma unroll
    for (int o = 0; o < 12; ++o) {
      float r0 = racc[n*24 + o*2 + 0];
      float r1 = racc[n*24 + o*2 + 1];
      ss += r0;
      v0 += r1 * s_ori[o*3+0];
      v1 += r1 * s_ori[o*3+1];
      v2 += r1 * s_ori[o*3+2];
    }
    atomicAdd(&s_part[bt], ss*sc);
    atomicAdd(&s_part[8 + bt*3 + 0], v0*sc);
    atomicAdd(&s_part[8 + bt*3 + 1], v1*sc);
    atomicAdd(&s_part[8 + bt*3 + 2], v2*sc);
  }
  __syncthreads();
  if (tid < 32) atomicAdd(&out[tid], s_part[tid]);
}

extern "C" void kernel_launch(void* const* d_in, const int* in_sizes, int n_in,
                              void* d_out, int out_size, void* d_ws, size_t ws_size,
                              hipStream_t stream) {
  const float* pos    = (const float*)d_in[0];
  const float* x      = (const float*)d_in[1];
  const int*   ei     = (const int*)d_in[2];
  const int*   batch  = (const int*)d_in[3];
  const float* sb_w1  = (const float*)d_in[4];
  const float* sb_b1  = (const float*)d_in[5];
  const float* sb_w2  = (const float*)d_in[6];
  const float* sb_b2  = (const float*)d_in[7];
  const float* fb_w1  = (const float*)d_in[8];
  const float* fb_b1  = (const float*)d_in[9];
  const float* fb_w2  = (const float*)d_in[10];
  const float* fb_b2  = (const float*)d_in[11];
  const float* emb_w  = (const float*)d_in[12];
  const float* conv_kw= (const float*)d_in[13];
  const float* fib_kw = (const float*)d_in[14];
  const float* conv_b = (const float*)d_in[15];
  const float* ln_s   = (const float*)d_in[16];
  const float* ln_b   = (const float*)d_in[17];
  const float* l1_w   = (const float*)d_in[18];
  const float* l1_b   = (const float*)d_in[19];
  const float* l2_w   = (const float*)d_in[20];
  const float* l2_b   = (const float*)d_in[21];
  const float* ro_w   = (const float*)d_in[22];
  const float* ro_b   = (const float*)d_in[23];

  float* ws_f   = (float*)d_ws;
  float* g_ori  = ws_f + OFF_ORI;
  float* g_fk   = ws_f + OFF_FK;
  float* g_h    = ws_f + OFF_H;
  float* g_xn   = ws_f + OFF_XN;
  float* g_racc = ws_f + OFF_RACC;
  int*   row_ptr= (int*)(ws_f + OFF_RP);
  int*   cursor = (int*)(ws_f + OFF_CUR);
  int*   e0s    = (int*)(ws_f + OFF_E0S);
  float4* rel4  = (float4*)(ws_f + OFF_REL);
  void*  kb     = (void*)(ws_f + OFF_KB);
  float* out_f  = (float*)d_out;

  int mode = (ws_size >= NEED_FP32) ? 0 : (ws_size >= NEED_BF16 ? 1 : 2);

  (void)hipMemsetAsync(g_racc, 0, 240000*sizeof(float), stream);
  k_setup<<<3, 256, 0, stream>>>(fb_w1, fb_b1, fb_w2, fb_b2, fib_kw, g_ori, g_fk);
  k_embed<<<512, 256, 0, stream>>>(x, emb_w, g_h);

  if (mode < 2) {
    (void)hipMemsetAsync(cursor, 0, (N_+1)*sizeof(int), stream);
    k_count<<<(E_+255)/256, 256, 0, stream>>>(ei, cursor);
    k_scan<<<1, 256, 0, stream>>>(cursor, row_ptr);
    k_scatter<<<(E_+255)/256, 256, 0, stream>>>(pos, ei, cursor, e0s, rel4);
    k_sortbins<<<(N_+255)/256, 256, 0, stream>>>(row_ptr, e0s, rel4);
    if (mode == 0)
      k_basis<0><<<(E_*ORI_/2+255)/256, 256, 0, stream>>>(rel4, sb_w1, sb_b1, sb_w2, sb_b2, g_ori, kb);
    else
      k_basis<1><<<(E_*ORI_/2+255)/256, 256, 0, stream>>>(rel4, sb_w1, sb_b1, sb_w2, sb_b2, g_ori, kb);
    for (int i = 0; i < 3; ++i) {
      if (mode == 0)
        k_aggr<0><<<N_, 256, 0, stream>>>(kb, row_ptr, e0s, conv_kw + i*4096,
                                          g_fk + i*9216, conv_b + i*64,
                                          ln_s + i*64, ln_b + i*64, g_h, g_xn);
      else
        k_aggr<1><<<N_, 256, 0, stream>>>(kb, row_ptr, e0s, conv_kw + i*4096,
                                          g_fk + i*9216, conv_b + i*64,
                                          ln_s + i*64, ln_b + i*64, g_h, g_xn);
      k_mlp<<<512, 256, 0, stream>>>(g_xn, g_h, l1_w + i*16384, l1_b + i*256,
                                     l2_w + i*16384, l2_b + i*64,
                                     ro_w + i*128, ro_b + i*2, g_racc);
    }
  } else {
    for (int i = 0; i < 3; ++i) {
      (void)hipMemsetAsync(g_xn, 0, 7680000*sizeof(float), stream);
      k_msg<<<1024, 256, 0, stream>>>(pos, ei, sb_w1, sb_b1, sb_w2, sb_b2,
                                      conv_kw + i*4096, g_ori, g_h, g_xn);
      k_convln<<<1024, 256, 0, stream>>>(g_xn, g_fk + i*9216, conv_b + i*64,
                                         ln_s + i*64, ln_b + i*64);
      k_mlp<<<512, 256, 0, stream>>>(g_xn, g_h, l1_w + i*16384, l1_b + i*256,
                                     l2_w + i*16384, l2_b + i*64,
                                     ro_w + i*128, ro_b + i*2, g_racc);
    }
  }
  (void)hipMemsetAsync(out_f, 0, 32*sizeof(float), stream);
  k_final<<<128, 256, 0, stream>>>(g_racc, batch, g_ori, out_f);
}

// Round 5
// 2119.433 us; speedup vs baseline: 2.4750x; 1.0411x over previous
//
#include <hip/hip_runtime.h>
#include <math.h>

namespace {
constexpr int N_   = 10000;
constexpr int E_   = 80000;
constexpr int ORI_ = 12;
constexpr int HC_  = 768;   // ORI*C
constexpr float EPS_ = 1e-6f;

// workspace layout (float units)
constexpr size_t OFF_ORI  = 0;                       // 64
constexpr size_t OFF_FK   = 64;                      // 3*144*64 = 27648
constexpr size_t OFF_H    = OFF_FK + 27648;          // 7,680,000
constexpr size_t OFF_XN   = OFF_H + 7680000;         // 7,680,000
constexpr size_t OFF_RACC = OFF_XN + 7680000;        // 240,000
constexpr size_t OFF_RP   = OFF_RACC + 240000;       // 10001 ints
constexpr size_t OFF_CUR  = OFF_RP + 10001;          // 10001 ints
constexpr size_t OFF_E0S  = OFF_CUR + 10001;         // 80000 ints
constexpr size_t OFF_REL  = ((OFF_E0S + 80000 + 3) / 4) * 4;  // 80000 float4
constexpr size_t OFF_KB   = ((OFF_REL + 320000 + 3) / 4) * 4;
constexpr size_t NEED_BF16 = OFF_KB * 4 + (size_t)E_ * ORI_ * 64 * 2;  // ~187 MB
}

__device__ __forceinline__ float gelu_f(float x) {
  float u = 0.7978845608028654f * (x + 0.044715f * x * x * x);
  float t = __expf(-2.0f * fabsf(u));
  float th = __fdividef(1.0f - t, 1.0f + t);
  th = copysignf(th, u);
  return 0.5f * x * (1.0f + th);
}

__device__ __forceinline__ void wave_sync() {
  asm volatile("s_waitcnt lgkmcnt(0)" ::: "memory");
  __builtin_amdgcn_wave_barrier();
}

__device__ __forceinline__ float wave_sum64(float v) {
#pragma unroll
  for (int off = 32; off > 0; off >>= 1) v += __shfl_xor(v, off, 64);
  return v;
}

__device__ __forceinline__ unsigned short f2bf(float x) {
  unsigned u = __float_as_uint(x);
  unsigned r = (u + 0x7fffu + ((u >> 16) & 1u)) >> 16;  // RNE
  return (unsigned short)r;
}

// ---------------------------------------------------------------------------
// Setup: grid=3 (one block per layer), all weights LDS-staged.
// ---------------------------------------------------------------------------
__global__ __launch_bounds__(256) void k_setup(
    const float* __restrict__ fb_w1, const float* __restrict__ fb_b1,
    const float* __restrict__ fb_w2, const float* __restrict__ fb_b2,
    const float* __restrict__ fib_kw,
    float* __restrict__ g_ori, float* __restrict__ g_fk) {
  __shared__ float s_ori[36];
  __shared__ float s_w1[192];
  __shared__ float s_b1[64], s_b2[64];
  __shared__ float s_w2[4096];
  __shared__ float s_fib[4096];
  __shared__ float s_h1[144*64];
  __shared__ float s_kb[144*64];
  int tid = threadIdx.x;
  int i = blockIdx.x;
  if (tid < 12) {
    const double PI = 3.14159265358979323846;
    double th = fmod(PI * (double)tid * (1.0 + sqrt(5.0)), 2.0 * PI);
    double ph = acos(1.0 - 2.0 * ((double)tid + 0.5) / 12.0);
    float sx = (float)(sin(ph) * cos(th));
    float sy = (float)(sin(ph) * sin(th));
    float sz = (float)cos(ph);
    s_ori[tid*3+0]=sx; s_ori[tid*3+1]=sy; s_ori[tid*3+2]=sz;
    if (i == 0) { g_ori[tid*3+0]=sx; g_ori[tid*3+1]=sy; g_ori[tid*3+2]=sz; }
  }
  for (int k = tid; k < 4096; k += 256) { s_w2[k] = fb_w2[k]; s_fib[k] = fib_kw[i*4096 + k]; }
  if (tid < 192) s_w1[tid] = fb_w1[tid];
  if (tid < 64) { s_b1[tid] = fb_b1[tid]; s_b2[tid] = fb_b2[tid]; }
  __syncthreads();
  int wid = tid >> 6, lane = tid & 63;
  for (int r = wid; r < 144; r += 4) {
    int p = r / 12, o = r % 12;
    float s = s_ori[p*3+0]*s_ori[o*3+0] + s_ori[p*3+1]*s_ori[o*3+1] + s_ori[p*3+2]*s_ori[o*3+2];
    float f1 = s, f2 = s*s, f3 = s*s*s;
    float a1 = s_b1[lane] + f1*s_w1[lane] + f2*s_w1[64+lane] + f3*s_w1[128+lane];
    s_h1[r*64+lane] = gelu_f(a1);
  }
  __syncthreads();
  for (int r = wid; r < 144; r += 4) {
    float a2 = s_b2[lane];
    for (int j = 0; j < 64; ++j) a2 += s_h1[r*64+j] * s_w2[j*64+lane];
    s_kb[r*64+lane] = gelu_f(a2);
  }
  __syncthreads();
  for (int r = wid; r < 144; r += 4) {
    float acc = 0.f;
    for (int j = 0; j < 64; ++j) acc += s_kb[r*64+j] * s_fib[j*64+lane];
    g_fk[i*9216 + r*64 + lane] = acc;
  }
}

// ---------------------------------------------------------------------------
// Embed
// ---------------------------------------------------------------------------
__global__ __launch_bounds__(256) void k_embed(
    const float* __restrict__ x, const float* __restrict__ emb_w,
    float* __restrict__ h) {
  __shared__ float s_w[16*64];
  int tid = threadIdx.x;
  for (int i = tid; i < 16*64; i += 256) s_w[i] = emb_w[i];
  __syncthreads();
  int wid = tid >> 6, lane = tid & 63;
  int nw = gridDim.x * 4;
  for (int n = blockIdx.x*4 + wid; n < N_; n += nw) {
    float acc = 0.f;
#pragma unroll
    for (int k = 0; k < 16; ++k) acc += x[n*16+k] * s_w[k*64+lane];
#pragma unroll
    for (int o = 0; o < ORI_; ++o) h[n*HC_ + o*64 + lane] = acc;
  }
}

// ---------------------------------------------------------------------------
// CSR build
// ---------------------------------------------------------------------------
__global__ __launch_bounds__(256) void k_count(const int* __restrict__ ei, int* __restrict__ cnt) {
  int e = blockIdx.x*256 + threadIdx.x;
  if (e < E_) atomicAdd(&cnt[ei[E_ + e]], 1);
}

__global__ __launch_bounds__(256) void k_scan(int* __restrict__ cnt, int* __restrict__ row_ptr) {
  __shared__ int s_sum[256];
  int tid = threadIdx.x;
  int start = tid * 40, end = min(start + 40, N_);
  int s = 0;
  for (int i = start; i < end; ++i) s += cnt[i];
  s_sum[tid] = s;
  __syncthreads();
  if (tid == 0) {
    int run = 0;
    for (int i = 0; i < 256; ++i) { int t = s_sum[i]; s_sum[i] = run; run += t; }
  }
  __syncthreads();
  int run = s_sum[tid];
  for (int i = start; i < end; ++i) { int c = cnt[i]; row_ptr[i] = run; cnt[i] = run; run += c; }
  if (tid == 0) row_ptr[N_] = E_;
}

__global__ __launch_bounds__(256) void k_scatter(
    const float* __restrict__ pos, const int* __restrict__ ei,
    int* __restrict__ cursor, int* __restrict__ e0s, float4* __restrict__ rel4) {
  int e = blockIdx.x*256 + threadIdx.x;
  if (e >= E_) return;
  int a = ei[e], b = ei[E_ + e];
  int slot = atomicAdd(&cursor[b], 1);
  float rx = pos[a*3+0]-pos[b*3+0];
  float ry = pos[a*3+1]-pos[b*3+1];
  float rz = pos[a*3+2]-pos[b*3+2];
  e0s[slot] = a;
  rel4[slot] = make_float4(rx, ry, rz, __int_as_float(e));
}

__global__ __launch_bounds__(256) void k_sortbins(
    const int* __restrict__ row_ptr, int* __restrict__ e0s, float4* __restrict__ rel4) {
  int n = blockIdx.x*256 + threadIdx.x;
  if (n >= N_) return;
  int lo = row_ptr[n], hi = row_ptr[n+1];
  for (int i = lo + 1; i < hi; ++i) {
    float4 key = rel4[i]; int kk = __float_as_int(key.w); int ke = e0s[i];
    int j = i - 1;
    while (j >= lo && __float_as_int(rel4[j].w) > kk) {
      rel4[j+1] = rel4[j]; e0s[j+1] = e0s[j]; --j;
    }
    rel4[j+1] = key; e0s[j+1] = ke;
  }
}

// ---------------------------------------------------------------------------
// Basis: 1 row/thread -> bf16 kb.  Output staged in XOR-swizzled LDS, then
// written out flat-coalesced (kills the 4x write amplification).
// kb layout: row r = s*12+o, 32 u32 (64 bf16) per row, linear.
// ---------------------------------------------------------------------------
__global__ __launch_bounds__(256) void k_basis_bf(
    const float4* __restrict__ rel4,
    const float* __restrict__ sb_w1, const float* __restrict__ sb_b1,
    const float* __restrict__ sb_w2, const float* __restrict__ sb_b2,
    const float* __restrict__ g_ori, unsigned* __restrict__ kb_u) {
  __shared__ float s_w1[14*64];
  __shared__ float s_w2[64*64];
  __shared__ float s_b1[64];
  __shared__ float s_b2[64];
  __shared__ float s_ori[36];
  __shared__ unsigned s_out[256*32];   // 32 KB, swizzled
  int tid = threadIdx.x;
  for (int i = tid; i < 14*64; i += 256) s_w1[i] = sb_w1[i];
  for (int i = tid; i < 64*64; i += 256) s_w2[i] = sb_w2[i];
  if (tid < 64) { s_b1[tid] = sb_b1[tid]; s_b2[tid] = sb_b2[tid]; }
  if (tid < 36) s_ori[tid] = g_ori[tid];
  __syncthreads();
  int r = blockIdx.x*256 + tid;        // grid is exact: 960000/256
  int s = r / 12, o = r - s*12;
  float4 rv = rel4[s];
  float rx = rv.x, ry = rv.y, rz = rv.z;
  float ox = s_ori[o*3+0], oy = s_ori[o*3+1], oz = s_ori[o*3+2];
  float i1 = rx*ox + ry*oy + rz*oz;
  float px = rx - i1*ox, py = ry - i1*oy, pz = rz - i1*oz;
  float i2 = sqrtf(px*px + py*py + pz*pz);
  float f[14];
  f[0]=i1; f[1]=i2; f[2]=i1*i1; f[3]=i1*i2; f[4]=i2*i1; f[5]=i2*i2;
  f[6]=f[2]*i1; f[7]=f[2]*i2; f[8]=f[3]*i1; f[9]=f[3]*i2;
  f[10]=f[4]*i1; f[11]=f[4]*i2; f[12]=f[5]*i1; f[13]=f[5]*i2;
  float h1[64];
#pragma unroll
  for (int j4 = 0; j4 < 16; ++j4) {
    float4 a = *(const float4*)&s_b1[j4*4];
#pragma unroll
    for (int p = 0; p < 14; ++p) {
      float4 w = *(const float4*)&s_w1[p*64 + j4*4];
      a.x += f[p]*w.x; a.y += f[p]*w.y; a.z += f[p]*w.z; a.w += f[p]*w.w;
    }
    h1[j4*4+0]=gelu_f(a.x); h1[j4*4+1]=gelu_f(a.y);
    h1[j4*4+2]=gelu_f(a.z); h1[j4*4+3]=gelu_f(a.w);
  }
  unsigned outw[32];
#pragma unroll 1
  for (int c4 = 0; c4 < 16; ++c4) {
    float4 a = *(const float4*)&s_b2[c4*4];
#pragma unroll
    for (int j = 0; j < 64; ++j) {
      float4 w = *(const float4*)&s_w2[j*64 + c4*4];
      float hv = h1[j];
      a.x += hv*w.x; a.y += hv*w.y; a.z += hv*w.z; a.w += hv*w.w;
    }
    a.x = gelu_f(a.x); a.y = gelu_f(a.y); a.z = gelu_f(a.z); a.w = gelu_f(a.w);
    outw[c4*2+0] = (unsigned)f2bf(a.x) | ((unsigned)f2bf(a.y) << 16);
    outw[c4*2+1] = (unsigned)f2bf(a.z) | ((unsigned)f2bf(a.w) << 16);
  }
  // stage to LDS, swizzled at uint4 granularity (bank-spread writes)
  uint4* s_out4 = (uint4*)s_out;
#pragma unroll
  for (int g = 0; g < 8; ++g) {
    s_out4[tid*8 + (g ^ (tid & 7))] =
        make_uint4(outw[g*4+0], outw[g*4+1], outw[g*4+2], outw[g*4+3]);
  }
  __syncthreads();
  // flat coalesced write-out (unswizzle on LDS read)
  size_t base = (size_t)blockIdx.x * 8192;
  for (int k = tid; k < 8192; k += 256) {
    int row = k >> 5, c = k & 31, g = c >> 2, q = c & 3;
    kb_u[base + k] = s_out[(row << 5) + ((g ^ (row & 7)) << 2) + q];
  }
}

// ---------------------------------------------------------------------------
// Fused aggregation + conv-mix + LayerNorm.  Block = node, wave = ori.
// kb rows loaded COALESCED (lane=word) -> per-wave LDS buffer -> broadcast
// ds_read_b128 dot against ck held in 64 VGPRs.  Next edge's kb row and
// h row are prefetched into registers during the current dot.
// ---------------------------------------------------------------------------
__global__ __launch_bounds__(256) void k_aggr_bf(
    const unsigned* __restrict__ kb_u, const int* __restrict__ row_ptr,
    const int* __restrict__ e0s, const float* __restrict__ ck,
    const float* __restrict__ g_fk_i, const float* __restrict__ conv_b,
    const float* __restrict__ ln_s, const float* __restrict__ ln_b,
    const float* __restrict__ h, float* __restrict__ xn) {
  __shared__ float s_fk[9216];
  __shared__ float s_x1[768];
  __shared__ float s_cb[64], s_ls[64], s_lb[64];
  __shared__ unsigned s_row[4][2][32];
  int tid = threadIdx.x;
  int wid = tid >> 6, lane = tid & 63;
  for (int i = tid; i < 9216; i += 256) s_fk[i] = g_fk_i[i];
  if (tid < 64) { s_cb[tid]=conv_b[tid]; s_ls[tid]=ln_s[tid]; s_lb[tid]=ln_b[tid]; }
  float ckreg[64];
#pragma unroll
  for (int j = 0; j < 64; ++j) ckreg[j] = ck[j*64 + lane];
  __syncthreads();
  int n = blockIdx.x;
  int lo = row_ptr[n], hi = row_ptr[n+1];
  for (int o = wid; o < 12; o += 4) {
    float acc = 0.f;
    if (lo < hi) {
      unsigned kn = 0; float hn;
      if (lane < 32) kn = kb_u[(size_t)(lo*12 + o)*32 + lane];
      hn = h[(size_t)e0s[lo]*HC_ + o*64 + lane];
      int buf = 0;
      for (int s = lo; s < hi; ++s) {
        unsigned kcur = kn; float hcur = hn;
        if (s + 1 < hi) {
          if (lane < 32) kn = kb_u[(size_t)((s+1)*12 + o)*32 + lane];
          hn = h[(size_t)e0s[s+1]*HC_ + o*64 + lane];
        }
        if (lane < 32) s_row[wid][buf][lane] = kcur;
        wave_sync();
        float kc = 0.f;
        const uint4* rp = (const uint4*)s_row[wid][buf];
#pragma unroll
        for (int g = 0; g < 8; ++g) {
          uint4 v = rp[g];
#pragma unroll
          for (int q = 0; q < 4; ++q) {
            unsigned w = (&v.x)[q];
            int j2 = g*4 + q;
            kc += __uint_as_float(w << 16) * ckreg[2*j2]
                + __uint_as_float(w & 0xffff0000u) * ckreg[2*j2+1];
          }
        }
        acc += hcur * kc;
        buf ^= 1;
      }
    }
    s_x1[o*64 + lane] = acc;
  }
  __syncthreads();
  for (int p = wid; p < 12; p += 4) {
    float a = 0.f;
#pragma unroll
    for (int o = 0; o < 12; ++o) a += s_x1[o*64+lane] * s_fk[(p*12+o)*64 + lane];
    a = a * (1.0f/12.0f) + s_cb[lane];
    float s1 = wave_sum64(a);
    float s2 = wave_sum64(a*a);
    float mu = s1 * (1.0f/64.0f);
    float var = s2 * (1.0f/64.0f) - mu*mu;
    xn[(size_t)n*HC_ + p*64 + lane] = (a - mu) * rsqrtf(var + EPS_) * s_ls[lane] + s_lb[lane];
  }
}

// ---------------------------------------------------------------------------
// Legacy (small-ws fallback)
// ---------------------------------------------------------------------------
__global__ __launch_bounds__(256) void k_msg(
    const float* __restrict__ pos, const int* __restrict__ ei,
    const float* __restrict__ sb_w1, const float* __restrict__ sb_b1,
    const float* __restrict__ sb_w2, const float* __restrict__ sb_b2,
    const float* __restrict__ ckw, const float* __restrict__ g_ori,
    const float* __restrict__ h, float* __restrict__ x1) {
  __shared__ float s_w1[14*64];
  __shared__ float s_b1[64];
  __shared__ float s_w2[64*64];
  __shared__ float s_b2[64];
  __shared__ float s_ck[64*64];
  __shared__ float s_ori[36];
  __shared__ float s_scr[4][2][64];
  int tid = threadIdx.x;
  for (int i = tid; i < 14*64; i += 256) s_w1[i] = sb_w1[i];
  for (int i = tid; i < 64*64; i += 256) { s_w2[i] = sb_w2[i]; s_ck[i] = ckw[i]; }
  if (tid < 64) { s_b1[tid] = sb_b1[tid]; s_b2[tid] = sb_b2[tid]; }
  if (tid < 36) s_ori[tid] = g_ori[tid];
  __syncthreads();
  int wid = tid >> 6, lane = tid & 63;
  int nw = gridDim.x * 4;
  const int* e0 = ei; const int* e1 = ei + E_;
  for (int e = blockIdx.x*4 + wid; e < E_; e += nw) {
    int a = e0[e], b = e1[e];
    float rx = pos[a*3+0]-pos[b*3+0];
    float ry = pos[a*3+1]-pos[b*3+1];
    float rz = pos[a*3+2]-pos[b*3+2];
    const float* hrow = h + a*HC_;
    float* xrow = x1 + b*HC_;
#pragma unroll 1
    for (int o = 0; o < ORI_; ++o) {
      float ox = s_ori[o*3+0], oy = s_ori[o*3+1], oz = s_ori[o*3+2];
      float i1 = rx*ox + ry*oy + rz*oz;
      float px = rx - i1*ox, py = ry - i1*oy, pz = rz - i1*oz;
      float i2 = sqrtf(px*px + py*py + pz*pz);
      float f[14];
      f[0]=i1; f[1]=i2; f[2]=i1*i1; f[3]=i1*i2; f[4]=i2*i1; f[5]=i2*i2;
      f[6]=f[2]*i1; f[7]=f[2]*i2; f[8]=f[3]*i1; f[9]=f[3]*i2;
      f[10]=f[4]*i1; f[11]=f[4]*i2; f[12]=f[5]*i1; f[13]=f[5]*i2;
      float a1 = s_b1[lane];
#pragma unroll
      for (int p = 0; p < 14; ++p) a1 += f[p] * s_w1[p*64+lane];
      a1 = gelu_f(a1);
      s_scr[wid][0][lane] = a1; wave_sync();
      float a2 = s_b2[lane];
      for (int j = 0; j < 64; ++j) a2 += s_scr[wid][0][j] * s_w2[j*64+lane];
      a2 = gelu_f(a2);
      s_scr[wid][1][lane] = a2; wave_sync();
      float kc = 0.f;
      for (int j = 0; j < 64; ++j) kc += s_scr[wid][1][j] * s_ck[j*64+lane];
      float m = hrow[o*64+lane] * kc;
      atomicAdd(&xrow[o*64+lane], m);
    }
  }
}

__global__ __launch_bounds__(256) void k_convln(
    float* __restrict__ x1, const float* __restrict__ g_fk_i,
    const float* __restrict__ conv_b, const float* __restrict__ ln_s,
    const float* __restrict__ ln_b) {
  __shared__ float s_fk[9216];
  __shared__ float s_cb[64], s_ls[64], s_lb[64];
  int tid = threadIdx.x;
  for (int i = tid; i < 9216; i += 256) s_fk[i] = g_fk_i[i];
  if (tid < 64) { s_cb[tid]=conv_b[tid]; s_ls[tid]=ln_s[tid]; s_lb[tid]=ln_b[tid]; }
  __syncthreads();
  int wid = tid >> 6, lane = tid & 63;
  int nw = gridDim.x * 4;
  for (int n = blockIdx.x*4 + wid; n < N_; n += nw) {
    float xr[12];
#pragma unroll
    for (int o = 0; o < 12; ++o) xr[o] = x1[n*HC_ + o*64 + lane];
    float xo[12];
#pragma unroll
    for (int p = 0; p < 12; ++p) {
      float acc = 0.f;
#pragma unroll
      for (int o = 0; o < 12; ++o) acc += xr[o] * s_fk[(p*12+o)*64 + lane];
      acc = acc * (1.0f/12.0f) + s_cb[lane];
      float s1 = wave_sum64(acc);
      float s2 = wave_sum64(acc*acc);
      float mu = s1 * (1.0f/64.0f);
      float var = s2 * (1.0f/64.0f) - mu*mu;
      xo[p] = (acc - mu) * rsqrtf(var + EPS_) * s_ls[lane] + s_lb[lane];
    }
#pragma unroll
    for (int p = 0; p < 12; ++p) x1[n*HC_ + p*64 + lane] = xo[p];
  }
}

// ---------------------------------------------------------------------------
// Node MLP 64->256->64 + residual + readout (4 rows/wave register blocking)
// ---------------------------------------------------------------------------
__global__ __launch_bounds__(256) void k_mlp(
    const float* __restrict__ xn, float* __restrict__ h,
    const float* __restrict__ l1_w, const float* __restrict__ l1_b,
    const float* __restrict__ l2_w, const float* __restrict__ l2_b,
    const float* __restrict__ ro_w, const float* __restrict__ ro_b,
    float* __restrict__ racc) {
  __shared__ float s_w1[64*256];
  __shared__ float s_w2t[64*256];
  __shared__ float s_b1[256];
  __shared__ float s_b2[64];
  __shared__ float s_ro[128];
  __shared__ float s_x[4][4][64];
  __shared__ float s_hm[4][4][256];
  int tid = threadIdx.x;
  for (int k = tid; k < 16384; k += 256) {
    s_w1[k] = l1_w[k];
    int j = k >> 6, l = k & 63;
    int jb = j >> 2, q = j & 3;
    s_w2t[l*256 + ((jb ^ (l & 7)) << 2) + q] = l2_w[k];
  }
  s_b1[tid] = l1_b[tid];
  if (tid < 64) s_b2[tid] = l2_b[tid];
  if (tid < 128) s_ro[tid] = ro_w[tid];
  __syncthreads();
  float rb0 = ro_b[0], rb1 = ro_b[1];
  int wid = tid >> 6, lane = tid & 63;
  int lx = lane & 7;
  int nw = gridDim.x * 4;
  const float4* w2row = (const float4*)&s_w2t[lane*256];
  for (int g = blockIdx.x*4 + wid; g < N_*ORI_/4; g += nw) {
    int r0 = g * 4;
#pragma unroll
    for (int rr = 0; rr < 4; ++rr) s_x[wid][rr][lane] = xn[(size_t)(r0+rr)*64 + lane];
    wave_sync();
    float4 b1v = *(const float4*)&s_b1[4*lane];
    float4 m[4] = {b1v, b1v, b1v, b1v};
#pragma unroll
    for (int c4 = 0; c4 < 16; ++c4) {
      float4 xv[4];
#pragma unroll
      for (int rr = 0; rr < 4; ++rr) xv[rr] = *(const float4*)&s_x[wid][rr][c4*4];
#pragma unroll
      for (int cc = 0; cc < 4; ++cc) {
        float4 w = *(const float4*)&s_w1[(c4*4+cc)*256 + 4*lane];
#pragma unroll
        for (int rr = 0; rr < 4; ++rr) {
          float xs = (&xv[rr].x)[cc];
          m[rr].x += xs*w.x; m[rr].y += xs*w.y; m[rr].z += xs*w.z; m[rr].w += xs*w.w;
        }
      }
    }
#pragma unroll
    for (int rr = 0; rr < 4; ++rr) {
      s_hm[wid][rr][4*lane+0] = gelu_f(m[rr].x);
      s_hm[wid][rr][4*lane+1] = gelu_f(m[rr].y);
      s_hm[wid][rr][4*lane+2] = gelu_f(m[rr].z);
      s_hm[wid][rr][4*lane+3] = gelu_f(m[rr].w);
    }
    wave_sync();
    float acc[4];
#pragma unroll
    for (int rr = 0; rr < 4; ++rr) acc[rr] = s_b2[lane];
#pragma unroll 8
    for (int jb = 0; jb < 64; ++jb) {
      float4 w = w2row[jb ^ lx];
#pragma unroll
      for (int rr = 0; rr < 4; ++rr) {
        float4 hm4 = *(const float4*)&s_hm[wid][rr][jb*4];
        acc[rr] += hm4.x*w.x + hm4.y*w.y + hm4.z*w.z + hm4.w*w.w;
      }
    }
#pragma unroll
    for (int rr = 0; rr < 4; ++rr) {
      size_t idx = (size_t)(r0+rr)*64 + lane;
      float hnew = acc[rr] + h[idx];
      h[idx] = hnew;
      float v0 = wave_sum64(hnew * s_ro[lane*2+0]);
      float v1 = wave_sum64(hnew * s_ro[lane*2+1]);
      if (lane == 0) {
        racc[(r0+rr)*2+0] += v0 + rb0;
        racc[(r0+rr)*2+1] += v1 + rb1;
      }
    }
  }
}

// ---------------------------------------------------------------------------
// Final segment-sum
// ---------------------------------------------------------------------------
__global__ __launch_bounds__(256) void k_final(
    const float* __restrict__ racc, const int* __restrict__ batch,
    const float* __restrict__ g_ori, float* __restrict__ out) {
  __shared__ float s_part[32];
  __shared__ float s_ori[36];
  int tid = threadIdx.x;
  if (tid < 32) s_part[tid] = 0.f;
  if (tid < 36) s_ori[tid] = g_ori[tid];
  __syncthreads();
  const float sc = 1.0f / 36.0f;
  for (int n = blockIdx.x*256 + tid; n < N_; n += gridDim.x*256) {
    int bt = batch[n];
    float ss = 0.f, v0 = 0.f, v1 = 0.f, v2 = 0.f;
#pragma unroll
    for (int o = 0; o < 12; ++o) {
      float r0 = racc[n*24 + o*2 + 0];
      float r1 = racc[n*24 + o*2 + 1];
      ss += r0;
      v0 += r1 * s_ori[o*3+0];
      v1 += r1 * s_ori[o*3+1];
      v2 += r1 * s_ori[o*3+2];
    }
    atomicAdd(&s_part[bt], ss*sc);
    atomicAdd(&s_part[8 + bt*3 + 0], v0*sc);
    atomicAdd(&s_part[8 + bt*3 + 1], v1*sc);
    atomicAdd(&s_part[8 + bt*3 + 2], v2*sc);
  }
  __syncthreads();
  if (tid < 32) atomicAdd(&out[tid], s_part[tid]);
}

extern "C" void kernel_launch(void* const* d_in, const int* in_sizes, int n_in,
                              void* d_out, int out_size, void* d_ws, size_t ws_size,
                              hipStream_t stream) {
  const float* pos    = (const float*)d_in[0];
  const float* x      = (const float*)d_in[1];
  const int*   ei     = (const int*)d_in[2];
  const int*   batch  = (const int*)d_in[3];
  const float* sb_w1  = (const float*)d_in[4];
  const float* sb_b1  = (const float*)d_in[5];
  const float* sb_w2  = (const float*)d_in[6];
  const float* sb_b2  = (const float*)d_in[7];
  const float* fb_w1  = (const float*)d_in[8];
  const float* fb_b1  = (const float*)d_in[9];
  const float* fb_w2  = (const float*)d_in[10];
  const float* fb_b2  = (const float*)d_in[11];
  const float* emb_w  = (const float*)d_in[12];
  const float* conv_kw= (const float*)d_in[13];
  const float* fib_kw = (const float*)d_in[14];
  const float* conv_b = (const float*)d_in[15];
  const float* ln_s   = (const float*)d_in[16];
  const float* ln_b   = (const float*)d_in[17];
  const float* l1_w   = (const float*)d_in[18];
  const float* l1_b   = (const float*)d_in[19];
  const float* l2_w   = (const float*)d_in[20];
  const float* l2_b   = (const float*)d_in[21];
  const float* ro_w   = (const float*)d_in[22];
  const float* ro_b   = (const float*)d_in[23];

  float* ws_f   = (float*)d_ws;
  float* g_ori  = ws_f + OFF_ORI;
  float* g_fk   = ws_f + OFF_FK;
  float* g_h    = ws_f + OFF_H;
  float* g_xn   = ws_f + OFF_XN;
  float* g_racc = ws_f + OFF_RACC;
  int*   row_ptr= (int*)(ws_f + OFF_RP);
  int*   cursor = (int*)(ws_f + OFF_CUR);
  int*   e0s    = (int*)(ws_f + OFF_E0S);
  float4* rel4  = (float4*)(ws_f + OFF_REL);
  unsigned* kb_u= (unsigned*)(ws_f + OFF_KB);
  float* out_f  = (float*)d_out;

  int mode = (ws_size >= NEED_BF16) ? 1 : 2;

  (void)hipMemsetAsync(g_racc, 0, 240000*sizeof(float), stream);
  k_setup<<<3, 256, 0, stream>>>(fb_w1, fb_b1, fb_w2, fb_b2, fib_kw, g_ori, g_fk);
  k_embed<<<512, 256, 0, stream>>>(x, emb_w, g_h);

  if (mode == 1) {
    (void)hipMemsetAsync(cursor, 0, (N_+1)*sizeof(int), stream);
    k_count<<<(E_+255)/256, 256, 0, stream>>>(ei, cursor);
    k_scan<<<1, 256, 0, stream>>>(cursor, row_ptr);
    k_scatter<<<(E_+255)/256, 256, 0, stream>>>(pos, ei, cursor, e0s, rel4);
    k_sortbins<<<(N_+255)/256, 256, 0, stream>>>(row_ptr, e0s, rel4);
    k_basis_bf<<<(E_*ORI_)/256, 256, 0, stream>>>(rel4, sb_w1, sb_b1, sb_w2, sb_b2, g_ori, kb_u);
    for (int i = 0; i < 3; ++i) {
      k_aggr_bf<<<N_, 256, 0, stream>>>(kb_u, row_ptr, e0s, conv_kw + i*4096,
                                        g_fk + i*9216, conv_b + i*64,
                                        ln_s + i*64, ln_b + i*64, g_h, g_xn);
      k_mlp<<<512, 256, 0, stream>>>(g_xn, g_h, l1_w + i*16384, l1_b + i*256,
                                     l2_w + i*16384, l2_b + i*64,
                                     ro_w + i*128, ro_b + i*2, g_racc);
    }
  } else {
    for (int i = 0; i < 3; ++i) {
      (void)hipMemsetAsync(g_xn, 0, 7680000*sizeof(float), stream);
      k_msg<<<1024, 256, 0, stream>>>(pos, ei, sb_w1, sb_b1, sb_w2, sb_b2,
                                      conv_kw + i*4096, g_ori, g_h, g_xn);
      k_convln<<<1024, 256, 0, stream>>>(g_xn, g_fk + i*9216, conv_b + i*64,
                                         ln_s + i*64, ln_b + i*64);
      k_mlp<<<512, 256, 0, stream>>>(g_xn, g_h, l1_w + i*16384, l1_b + i*256,
                                     l2_w + i*16384, l2_b + i*64,
                                     ro_w + i*128, ro_b + i*2, g_racc);
    }
  }
  (void)hipMemsetAsync(out_f, 0, 32*sizeof(float), stream);
  k_final<<<128, 256, 0, stream>>>(g_racc, batch, g_ori, out_f);
}

// Round 6
// 1263.972 us; speedup vs baseline: 4.1501x; 1.6768x over previous
//
#include <hip/hip_runtime.h>
#include <math.h>

namespace {
constexpr int N_   = 10000;
constexpr int E_   = 80000;
constexpr int ORI_ = 12;
constexpr int HC_  = 768;   // ORI*C
constexpr float EPS_ = 1e-6f;

// workspace layout (float units)
constexpr size_t OFF_ORI  = 0;                       // 64
constexpr size_t OFF_FK   = 64;                      // 3*144*64 = 27648
constexpr size_t OFF_H    = OFF_FK + 27648;          // 7,680,000
constexpr size_t OFF_XN   = OFF_H + 7680000;         // 7,680,000 (mode1: bf16 xn)
constexpr size_t OFF_RACC = OFF_XN + 7680000;        // 240,000
constexpr size_t OFF_RP   = OFF_RACC + 240000;       // 10001 ints
constexpr size_t OFF_CUR  = OFF_RP + 10001;          // 10001 ints
constexpr size_t OFF_E0S  = OFF_CUR + 10001;         // 80000 ints
constexpr size_t OFF_REL  = ((OFF_E0S + 80000 + 3) / 4) * 4;  // 80000 float4
constexpr size_t OFF_WP   = ((OFF_REL + 320000 + 3) / 4) * 4; // 3*32768 u16 = 49152 f
constexpr size_t OFF_KB   = OFF_WP + 49152;
constexpr size_t NEED_BF16 = OFF_KB * 4 + (size_t)E_ * ORI_ * 64 * 2;  // ~188 MB
}

typedef short bf16x8 __attribute__((ext_vector_type(8)));
typedef float f32x4  __attribute__((ext_vector_type(4)));

__device__ __forceinline__ float gelu_f(float x) {
  // 0.5x(1+tanh(0.79788456(x+0.044715x^3))) == x*t/(t+1), t=2^(x(a+b x^2))
  float x2 = x * x;
  float u  = x * fmaf(x2, 0.10294324f, 2.30220826f);
  float t  = __builtin_amdgcn_exp2f(u);
  float r  = __builtin_amdgcn_rcpf(t + 1.0f);
  return fmaf(-x, r, x);
}

__device__ __forceinline__ void wave_sync() {
  asm volatile("s_waitcnt lgkmcnt(0)" ::: "memory");
  __builtin_amdgcn_wave_barrier();
}

__device__ __forceinline__ float wave_sum64(float v) {
#pragma unroll
  for (int off = 32; off > 0; off >>= 1) v += __shfl_xor(v, off, 64);
  return v;
}

__device__ __forceinline__ unsigned short f2bf(float x) {
  unsigned u = __float_as_uint(x);
  unsigned r = (u + 0x7fffu + ((u >> 16) & 1u)) >> 16;  // RNE
  return (unsigned short)r;
}

// ---------------------------------------------------------------------------
// Setup: grid=3 (one block per layer), all weights LDS-staged.
// ---------------------------------------------------------------------------
__global__ __launch_bounds__(256) void k_setup(
    const float* __restrict__ fb_w1, const float* __restrict__ fb_b1,
    const float* __restrict__ fb_w2, const float* __restrict__ fb_b2,
    const float* __restrict__ fib_kw,
    float* __restrict__ g_ori, float* __restrict__ g_fk) {
  __shared__ float s_ori[36];
  __shared__ float s_w1[192];
  __shared__ float s_b1[64], s_b2[64];
  __shared__ float s_w2[4096];
  __shared__ float s_fib[4096];
  __shared__ float s_h1[144*64];
  __shared__ float s_kb[144*64];
  int tid = threadIdx.x;
  int i = blockIdx.x;
  if (tid < 12) {
    const double PI = 3.14159265358979323846;
    double th = fmod(PI * (double)tid * (1.0 + sqrt(5.0)), 2.0 * PI);
    double ph = acos(1.0 - 2.0 * ((double)tid + 0.5) / 12.0);
    float sx = (float)(sin(ph) * cos(th));
    float sy = (float)(sin(ph) * sin(th));
    float sz = (float)cos(ph);
    s_ori[tid*3+0]=sx; s_ori[tid*3+1]=sy; s_ori[tid*3+2]=sz;
    if (i == 0) { g_ori[tid*3+0]=sx; g_ori[tid*3+1]=sy; g_ori[tid*3+2]=sz; }
  }
  for (int k = tid; k < 4096; k += 256) { s_w2[k] = fb_w2[k]; s_fib[k] = fib_kw[i*4096 + k]; }
  if (tid < 192) s_w1[tid] = fb_w1[tid];
  if (tid < 64) { s_b1[tid] = fb_b1[tid]; s_b2[tid] = fb_b2[tid]; }
  __syncthreads();
  int wid = tid >> 6, lane = tid & 63;
  for (int r = wid; r < 144; r += 4) {
    int p = r / 12, o = r % 12;
    float s = s_ori[p*3+0]*s_ori[o*3+0] + s_ori[p*3+1]*s_ori[o*3+1] + s_ori[p*3+2]*s_ori[o*3+2];
    float f1 = s, f2 = s*s, f3 = s*s*s;
    float a1 = s_b1[lane] + f1*s_w1[lane] + f2*s_w1[64+lane] + f3*s_w1[128+lane];
    s_h1[r*64+lane] = gelu_f(a1);
  }
  __syncthreads();
  for (int r = wid; r < 144; r += 4) {
    float a2 = s_b2[lane];
    for (int j = 0; j < 64; ++j) a2 += s_h1[r*64+j] * s_w2[j*64+lane];
    s_kb[r*64+lane] = gelu_f(a2);
  }
  __syncthreads();
  for (int r = wid; r < 144; r += 4) {
    float acc = 0.f;
    for (int j = 0; j < 64; ++j) acc += s_kb[r*64+j] * s_fib[j*64+lane];
    g_fk[i*9216 + r*64 + lane] = acc;
  }
}

// ---------------------------------------------------------------------------
// Embed
// ---------------------------------------------------------------------------
__global__ __launch_bounds__(256) void k_embed(
    const float* __restrict__ x, const float* __restrict__ emb_w,
    float* __restrict__ h) {
  __shared__ float s_w[16*64];
  int tid = threadIdx.x;
  for (int i = tid; i < 16*64; i += 256) s_w[i] = emb_w[i];
  __syncthreads();
  int wid = tid >> 6, lane = tid & 63;
  int nw = gridDim.x * 4;
  for (int n = blockIdx.x*4 + wid; n < N_; n += nw) {
    float acc = 0.f;
#pragma unroll
    for (int k = 0; k < 16; ++k) acc += x[n*16+k] * s_w[k*64+lane];
#pragma unroll
    for (int o = 0; o < ORI_; ++o) h[n*HC_ + o*64 + lane] = acc;
  }
}

// ---------------------------------------------------------------------------
// CSR build
// ---------------------------------------------------------------------------
__global__ __launch_bounds__(256) void k_count(const int* __restrict__ ei, int* __restrict__ cnt) {
  int e = blockIdx.x*256 + threadIdx.x;
  if (e < E_) atomicAdd(&cnt[ei[E_ + e]], 1);
}

__global__ __launch_bounds__(256) void k_scan(int* __restrict__ cnt, int* __restrict__ row_ptr) {
  __shared__ int s_sum[256];
  int tid = threadIdx.x;
  int start = tid * 40, end = min(start + 40, N_);
  int s = 0;
  for (int i = start; i < end; ++i) s += cnt[i];
  s_sum[tid] = s;
  __syncthreads();
  if (tid == 0) {
    int run = 0;
    for (int i = 0; i < 256; ++i) { int t = s_sum[i]; s_sum[i] = run; run += t; }
  }
  __syncthreads();
  int run = s_sum[tid];
  for (int i = start; i < end; ++i) { int c = cnt[i]; row_ptr[i] = run; cnt[i] = run; run += c; }
  if (tid == 0) row_ptr[N_] = E_;
}

__global__ __launch_bounds__(256) void k_scatter(
    const float* __restrict__ pos, const int* __restrict__ ei,
    int* __restrict__ cursor, int* __restrict__ e0s, float4* __restrict__ rel4) {
  int e = blockIdx.x*256 + threadIdx.x;
  if (e >= E_) return;
  int a = ei[e], b = ei[E_ + e];
  int slot = atomicAdd(&cursor[b], 1);
  float rx = pos[a*3+0]-pos[b*3+0];
  float ry = pos[a*3+1]-pos[b*3+1];
  float rz = pos[a*3+2]-pos[b*3+2];
  e0s[slot] = a;
  rel4[slot] = make_float4(rx, ry, rz, __int_as_float(e));
}

__global__ __launch_bounds__(256) void k_sortbins(
    const int* __restrict__ row_ptr, int* __restrict__ e0s, float4* __restrict__ rel4) {
  int n = blockIdx.x*256 + threadIdx.x;
  if (n >= N_) return;
  int lo = row_ptr[n], hi = row_ptr[n+1];
  for (int i = lo + 1; i < hi; ++i) {
    float4 key = rel4[i]; int kk = __float_as_int(key.w); int ke = e0s[i];
    int j = i - 1;
    while (j >= lo && __float_as_int(rel4[j].w) > kk) {
      rel4[j+1] = rel4[j]; e0s[j+1] = e0s[j]; --j;
    }
    rel4[j+1] = key; e0s[j+1] = ke;
  }
}

// ---------------------------------------------------------------------------
// Basis: 1 row/thread -> bf16 kb, staged via swizzled LDS, coalesced writeout.
// ---------------------------------------------------------------------------
__global__ __launch_bounds__(256) void k_basis_bf(
    const float4* __restrict__ rel4,
    const float* __restrict__ sb_w1, const float* __restrict__ sb_b1,
    const float* __restrict__ sb_w2, const float* __restrict__ sb_b2,
    const float* __restrict__ g_ori, unsigned* __restrict__ kb_u) {
  __shared__ float s_w1[14*64];
  __shared__ float s_w2[64*64];
  __shared__ float s_b1[64];
  __shared__ float s_b2[64];
  __shared__ float s_ori[36];
  __shared__ unsigned s_out[256*32];   // 32 KB, swizzled
  int tid = threadIdx.x;
  for (int i = tid; i < 14*64; i += 256) s_w1[i] = sb_w1[i];
  for (int i = tid; i < 64*64; i += 256) s_w2[i] = sb_w2[i];
  if (tid < 64) { s_b1[tid] = sb_b1[tid]; s_b2[tid] = sb_b2[tid]; }
  if (tid < 36) s_ori[tid] = g_ori[tid];
  __syncthreads();
  int r = blockIdx.x*256 + tid;
  int s = r / 12, o = r - s*12;
  float4 rv = rel4[s];
  float rx = rv.x, ry = rv.y, rz = rv.z;
  float ox = s_ori[o*3+0], oy = s_ori[o*3+1], oz = s_ori[o*3+2];
  float i1 = rx*ox + ry*oy + rz*oz;
  float px = rx - i1*ox, py = ry - i1*oy, pz = rz - i1*oz;
  float i2 = sqrtf(px*px + py*py + pz*pz);
  float f[14];
  f[0]=i1; f[1]=i2; f[2]=i1*i1; f[3]=i1*i2; f[4]=i2*i1; f[5]=i2*i2;
  f[6]=f[2]*i1; f[7]=f[2]*i2; f[8]=f[3]*i1; f[9]=f[3]*i2;
  f[10]=f[4]*i1; f[11]=f[4]*i2; f[12]=f[5]*i1; f[13]=f[5]*i2;
  float h1[64];
#pragma unroll
  for (int j4 = 0; j4 < 16; ++j4) {
    float4 a = *(const float4*)&s_b1[j4*4];
#pragma unroll
    for (int p = 0; p < 14; ++p) {
      float4 w = *(const float4*)&s_w1[p*64 + j4*4];
      a.x += f[p]*w.x; a.y += f[p]*w.y; a.z += f[p]*w.z; a.w += f[p]*w.w;
    }
    h1[j4*4+0]=gelu_f(a.x); h1[j4*4+1]=gelu_f(a.y);
    h1[j4*4+2]=gelu_f(a.z); h1[j4*4+3]=gelu_f(a.w);
  }
  unsigned outw[32];
#pragma unroll 1
  for (int c4 = 0; c4 < 16; ++c4) {
    float4 a = *(const float4*)&s_b2[c4*4];
#pragma unroll
    for (int j = 0; j < 64; ++j) {
      float4 w = *(const float4*)&s_w2[j*64 + c4*4];
      float hv = h1[j];
      a.x += hv*w.x; a.y += hv*w.y; a.z += hv*w.z; a.w += hv*w.w;
    }
    a.x = gelu_f(a.x); a.y = gelu_f(a.y); a.z = gelu_f(a.z); a.w = gelu_f(a.w);
    outw[c4*2+0] = (unsigned)f2bf(a.x) | ((unsigned)f2bf(a.y) << 16);
    outw[c4*2+1] = (unsigned)f2bf(a.z) | ((unsigned)f2bf(a.w) << 16);
  }
  uint4* s_out4 = (uint4*)s_out;
#pragma unroll
  for (int g = 0; g < 8; ++g) {
    s_out4[tid*8 + (g ^ (tid & 7))] =
        make_uint4(outw[g*4+0], outw[g*4+1], outw[g*4+2], outw[g*4+3]);
  }
  __syncthreads();
  size_t base = (size_t)blockIdx.x * 8192;
  for (int k = tid; k < 8192; k += 256) {
    int row = k >> 5, c = k & 31, g = c >> 2, q = c & 3;
    kb_u[base + k] = s_out[(row << 5) + ((g ^ (row & 7)) << 2) + q];
  }
}

// ---------------------------------------------------------------------------
// Fused aggregation + conv-mix + LayerNorm.  Writes xn in BF16 (for MFMA MLP).
// ---------------------------------------------------------------------------
__global__ __launch_bounds__(256) void k_aggr_bf(
    const unsigned* __restrict__ kb_u, const int* __restrict__ row_ptr,
    const int* __restrict__ e0s, const float* __restrict__ ck,
    const float* __restrict__ g_fk_i, const float* __restrict__ conv_b,
    const float* __restrict__ ln_s, const float* __restrict__ ln_b,
    const float* __restrict__ h, unsigned short* __restrict__ xnb) {
  __shared__ float s_fk[9216];
  __shared__ float s_x1[768];
  __shared__ float s_cb[64], s_ls[64], s_lb[64];
  __shared__ unsigned s_row[4][2][32];
  int tid = threadIdx.x;
  int wid = tid >> 6, lane = tid & 63;
  for (int i = tid; i < 9216; i += 256) s_fk[i] = g_fk_i[i];
  if (tid < 64) { s_cb[tid]=conv_b[tid]; s_ls[tid]=ln_s[tid]; s_lb[tid]=ln_b[tid]; }
  float ckreg[64];
#pragma unroll
  for (int j = 0; j < 64; ++j) ckreg[j] = ck[j*64 + lane];
  __syncthreads();
  int n = blockIdx.x;
  int lo = row_ptr[n], hi = row_ptr[n+1];
  for (int o = wid; o < 12; o += 4) {
    float acc = 0.f;
    if (lo < hi) {
      unsigned kn = 0; float hn;
      if (lane < 32) kn = kb_u[(size_t)(lo*12 + o)*32 + lane];
      hn = h[(size_t)e0s[lo]*HC_ + o*64 + lane];
      int buf = 0;
      for (int s = lo; s < hi; ++s) {
        unsigned kcur = kn; float hcur = hn;
        if (s + 1 < hi) {
          if (lane < 32) kn = kb_u[(size_t)((s+1)*12 + o)*32 + lane];
          hn = h[(size_t)e0s[s+1]*HC_ + o*64 + lane];
        }
        if (lane < 32) s_row[wid][buf][lane] = kcur;
        wave_sync();
        float kc = 0.f;
        const uint4* rp = (const uint4*)s_row[wid][buf];
#pragma unroll
        for (int g = 0; g < 8; ++g) {
          uint4 v = rp[g];
#pragma unroll
          for (int q = 0; q < 4; ++q) {
            unsigned w = (&v.x)[q];
            int j2 = g*4 + q;
            kc += __uint_as_float(w << 16) * ckreg[2*j2]
                + __uint_as_float(w & 0xffff0000u) * ckreg[2*j2+1];
          }
        }
        acc += hcur * kc;
        buf ^= 1;
      }
    }
    s_x1[o*64 + lane] = acc;
  }
  __syncthreads();
  for (int p = wid; p < 12; p += 4) {
    float a = 0.f;
#pragma unroll
    for (int o = 0; o < 12; ++o) a += s_x1[o*64+lane] * s_fk[(p*12+o)*64 + lane];
    a = a * (1.0f/12.0f) + s_cb[lane];
    float s1 = wave_sum64(a);
    float s2 = wave_sum64(a*a);
    float mu = s1 * (1.0f/64.0f);
    float var = s2 * (1.0f/64.0f) - mu*mu;
    float v = (a - mu) * rsqrtf(var + EPS_) * s_ls[lane] + s_lb[lane];
    xnb[(size_t)n*HC_ + p*64 + lane] = f2bf(v);
  }
}

// ---------------------------------------------------------------------------
// Pack MLP weights into bf16 MFMA fragment order (once).
// w1p frag: lane = ((c>>3)&3)*16 + (j&15), half h=c>>5:  [jt][h][lane][c&7]
// w2p frag: lane = ((j>>3)&3)*16 + (c&15), kstep ks=j>>5: [ct*8+ks][lane][j&7]
// ---------------------------------------------------------------------------
__global__ __launch_bounds__(256) void k_pack(
    const float* __restrict__ l1_w, const float* __restrict__ l2_w,
    unsigned short* __restrict__ wp) {
  int i = blockIdx.x;
  unsigned short* w1p = wp + (size_t)i*32768;
  unsigned short* w2p = w1p + 16384;
  const float* w1 = l1_w + i*16384;
  const float* w2 = l2_w + i*16384;
  for (int k = threadIdx.x; k < 16384; k += 256) {
    int c = k >> 8, j = k & 255;          // w1[c][j]
    int jt = j >> 4, hh = c >> 5, gg = (c >> 3) & 3, kp = c & 7;
    int l = gg*16 + (j & 15);
    w1p[jt*1024 + hh*512 + l*8 + kp] = f2bf(w1[k]);
    int j2 = k >> 6, c2 = k & 63;         // w2[j2][c2]
    int ct = c2 >> 4, ks = j2 >> 5, g2 = (j2 >> 3) & 3, kp2 = j2 & 7;
    int l2 = g2*16 + (c2 & 15);
    w2p[(ct*8+ks)*512 + l2*8 + kp2] = f2bf(w2[k]);
  }
}

// ---------------------------------------------------------------------------
// Node MLP via MFMA (bf16): 512 threads = 8 waves, 16 rows per wave-iter.
// Stage1 transposed (hm^T = w1^T·xn^T) so C-frag -> ds_write_b64; stage2
// normal (out = hm·w2).  Fused residual + readout.
// ---------------------------------------------------------------------------
__global__ __launch_bounds__(512) void k_mlp_mfma(
    const unsigned short* __restrict__ xnb, float* __restrict__ h,
    const unsigned short* __restrict__ w1p, const unsigned short* __restrict__ w2p,
    const float* __restrict__ l1_b, const float* __restrict__ l2_b,
    const float* __restrict__ ro_w, const float* __restrict__ ro_b,
    float* __restrict__ racc) {
  __shared__ unsigned short s_w1p[16384];
  __shared__ unsigned short s_w2p[16384];
  __shared__ float s_b1[256];
  __shared__ float s_b2[64];
  __shared__ float s_ro[128];
  __shared__ unsigned short s_hm[8][16*272];   // 272 bf16 row stride (pad)
  int tid = threadIdx.x;
  {
    const uint4* a4 = (const uint4*)w1p;  uint4* d4 = (uint4*)s_w1p;
    const uint4* b4 = (const uint4*)w2p;  uint4* e4 = (uint4*)s_w2p;
    for (int k = tid; k < 2048; k += 512) { d4[k] = a4[k]; e4[k] = b4[k]; }
  }
  if (tid < 256) s_b1[tid] = l1_b[tid];
  if (tid < 64)  s_b2[tid] = l2_b[tid];
  if (tid < 128) s_ro[tid] = ro_w[tid];
  __syncthreads();
  int wid = tid >> 6, lane = tid & 63;
  int g = lane >> 4, m = lane & 15;
  float rb0 = ro_b[0], rb1 = ro_b[1];
  float b2v[4], rw0[4], rw1[4];
#pragma unroll
  for (int ct = 0; ct < 4; ++ct) {
    b2v[ct] = s_b2[ct*16 + m];
    rw0[ct] = s_ro[(ct*16+m)*2+0];
    rw1[ct] = s_ro[(ct*16+m)*2+1];
  }
  unsigned short* hm = s_hm[wid];
  int nwg = gridDim.x * 8;
  for (int rg = blockIdx.x*8 + wid; rg < 7500; rg += nwg) {
    int r0 = rg * 16;
    // xn B-fragments (B[k=c][col=r]: lane holds row r0+m, c = g*8..+7)
    bf16x8 xb0 = *(const bf16x8*)(xnb + (size_t)(r0 + m)*64 + g*8);
    bf16x8 xb1 = *(const bf16x8*)(xnb + (size_t)(r0 + m)*64 + 32 + g*8);
    wave_sync();
    // ---- stage 1: hm^T[j][r] = gelu(w1T·xnT + b1)
#pragma unroll 4
    for (int jt = 0; jt < 16; ++jt) {
      bf16x8 a0 = *(const bf16x8*)(s_w1p + jt*1024 + lane*8);
      bf16x8 a1 = *(const bf16x8*)(s_w1p + jt*1024 + 512 + lane*8);
      f32x4 acc = {0.f, 0.f, 0.f, 0.f};
      acc = __builtin_amdgcn_mfma_f32_16x16x32_bf16(a0, xb0, acc, 0, 0, 0);
      acc = __builtin_amdgcn_mfma_f32_16x16x32_bf16(a1, xb1, acc, 0, 0, 0);
      float4 b1v = *(const float4*)&s_b1[jt*16 + g*4];
      float g0 = gelu_f(acc[0] + b1v.x);
      float g1 = gelu_f(acc[1] + b1v.y);
      float g2 = gelu_f(acc[2] + b1v.z);
      float g3 = gelu_f(acc[3] + b1v.w);
      unsigned wa = (unsigned)f2bf(g0) | ((unsigned)f2bf(g1) << 16);
      unsigned wb = (unsigned)f2bf(g2) | ((unsigned)f2bf(g3) << 16);
      *(uint2*)(hm + m*272 + jt*16 + g*4) = make_uint2(wa, wb);
    }
    wave_sync();
    // ---- stage 2: out[r][c] = hm·w2 + b2 (+ h residual)
    f32x4 acc2[4];
#pragma unroll
    for (int ct = 0; ct < 4; ++ct) acc2[ct] = (f32x4){0.f, 0.f, 0.f, 0.f};
#pragma unroll
    for (int ks = 0; ks < 8; ++ks) {
      bf16x8 a2 = *(const bf16x8*)(hm + m*272 + ks*32 + g*8);
#pragma unroll
      for (int ct = 0; ct < 4; ++ct) {
        bf16x8 bf = *(const bf16x8*)(s_w2p + (ct*8+ks)*512 + lane*8);
        acc2[ct] = __builtin_amdgcn_mfma_f32_16x16x32_bf16(a2, bf, acc2[ct], 0, 0, 0);
      }
    }
    wave_sync();
    // ---- residual + h update + readout (row r = r0 + 4g + reg)
#pragma unroll
    for (int reg = 0; reg < 4; ++reg) {
      int r = r0 + 4*g + reg;
      float v0 = 0.f, v1 = 0.f;
#pragma unroll
      for (int ct = 0; ct < 4; ++ct) {
        size_t idx = (size_t)r*64 + ct*16 + m;
        float hnew = acc2[ct][reg] + b2v[ct] + h[idx];
        h[idx] = hnew;
        v0 += hnew * rw0[ct];
        v1 += hnew * rw1[ct];
      }
#pragma unroll
      for (int off = 8; off > 0; off >>= 1) {
        v0 += __shfl_xor(v0, off, 16);
        v1 += __shfl_xor(v1, off, 16);
      }
      if (m == 0) {
        racc[r*2+0] += v0 + rb0;
        racc[r*2+1] += v1 + rb1;
      }
    }
  }
}

// ---------------------------------------------------------------------------
// Legacy (small-ws fallback) kernels
// ---------------------------------------------------------------------------
__global__ __launch_bounds__(256) void k_msg(
    const float* __restrict__ pos, const int* __restrict__ ei,
    const float* __restrict__ sb_w1, const float* __restrict__ sb_b1,
    const float* __restrict__ sb_w2, const float* __restrict__ sb_b2,
    const float* __restrict__ ckw, const float* __restrict__ g_ori,
    const float* __restrict__ h, float* __restrict__ x1) {
  __shared__ float s_w1[14*64];
  __shared__ float s_b1[64];
  __shared__ float s_w2[64*64];
  __shared__ float s_b2[64];
  __shared__ float s_ck[64*64];
  __shared__ float s_ori[36];
  __shared__ float s_scr[4][2][64];
  int tid = threadIdx.x;
  for (int i = tid; i < 14*64; i += 256) s_w1[i] = sb_w1[i];
  for (int i = tid; i < 64*64; i += 256) { s_w2[i] = sb_w2[i]; s_ck[i] = ckw[i]; }
  if (tid < 64) { s_b1[tid] = sb_b1[tid]; s_b2[tid] = sb_b2[tid]; }
  if (tid < 36) s_ori[tid] = g_ori[tid];
  __syncthreads();
  int wid = tid >> 6, lane = tid & 63;
  int nw = gridDim.x * 4;
  const int* e0 = ei; const int* e1 = ei + E_;
  for (int e = blockIdx.x*4 + wid; e < E_; e += nw) {
    int a = e0[e], b = e1[e];
    float rx = pos[a*3+0]-pos[b*3+0];
    float ry = pos[a*3+1]-pos[b*3+1];
    float rz = pos[a*3+2]-pos[b*3+2];
    const float* hrow = h + a*HC_;
    float* xrow = x1 + b*HC_;
#pragma unroll 1
    for (int o = 0; o < ORI_; ++o) {
      float ox = s_ori[o*3+0], oy = s_ori[o*3+1], oz = s_ori[o*3+2];
      float i1 = rx*ox + ry*oy + rz*oz;
      float px = rx - i1*ox, py = ry - i1*oy, pz = rz - i1*oz;
      float i2 = sqrtf(px*px + py*py + pz*pz);
      float f[14];
      f[0]=i1; f[1]=i2; f[2]=i1*i1; f[3]=i1*i2; f[4]=i2*i1; f[5]=i2*i2;
      f[6]=f[2]*i1; f[7]=f[2]*i2; f[8]=f[3]*i1; f[9]=f[3]*i2;
      f[10]=f[4]*i1; f[11]=f[4]*i2; f[12]=f[5]*i1; f[13]=f[5]*i2;
      float a1 = s_b1[lane];
#pragma unroll
      for (int p = 0; p < 14; ++p) a1 += f[p] * s_w1[p*64+lane];
      a1 = gelu_f(a1);
      s_scr[wid][0][lane] = a1; wave_sync();
      float a2 = s_b2[lane];
      for (int j = 0; j < 64; ++j) a2 += s_scr[wid][0][j] * s_w2[j*64+lane];
      a2 = gelu_f(a2);
      s_scr[wid][1][lane] = a2; wave_sync();
      float kc = 0.f;
      for (int j = 0; j < 64; ++j) kc += s_scr[wid][1][j] * s_ck[j*64+lane];
      float msg = hrow[o*64+lane] * kc;
      atomicAdd(&xrow[o*64+lane], msg);
    }
  }
}

__global__ __launch_bounds__(256) void k_convln(
    float* __restrict__ x1, const float* __restrict__ g_fk_i,
    const float* __restrict__ conv_b, const float* __restrict__ ln_s,
    const float* __restrict__ ln_b) {
  __shared__ float s_fk[9216];
  __shared__ float s_cb[64], s_ls[64], s_lb[64];
  int tid = threadIdx.x;
  for (int i = tid; i < 9216; i += 256) s_fk[i] = g_fk_i[i];
  if (tid < 64) { s_cb[tid]=conv_b[tid]; s_ls[tid]=ln_s[tid]; s_lb[tid]=ln_b[tid]; }
  __syncthreads();
  int wid = tid >> 6, lane = tid & 63;
  int nw = gridDim.x * 4;
  for (int n = blockIdx.x*4 + wid; n < N_; n += nw) {
    float xr[12];
#pragma unroll
    for (int o = 0; o < 12; ++o) xr[o] = x1[n*HC_ + o*64 + lane];
    float xo[12];
#pragma unroll
    for (int p = 0; p < 12; ++p) {
      float acc = 0.f;
#pragma unroll
      for (int o = 0; o < 12; ++o) acc += xr[o] * s_fk[(p*12+o)*64 + lane];
      acc = acc * (1.0f/12.0f) + s_cb[lane];
      float s1 = wave_sum64(acc);
      float s2 = wave_sum64(acc*acc);
      float mu = s1 * (1.0f/64.0f);
      float var = s2 * (1.0f/64.0f) - mu*mu;
      xo[p] = (acc - mu) * rsqrtf(var + EPS_) * s_ls[lane] + s_lb[lane];
    }
#pragma unroll
    for (int p = 0; p < 12; ++p) x1[n*HC_ + p*64 + lane] = xo[p];
  }
}

__global__ __launch_bounds__(256) void k_mlp(
    const float* __restrict__ xn, float* __restrict__ h,
    const float* __restrict__ l1_w, const float* __restrict__ l1_b,
    const float* __restrict__ l2_w, const float* __restrict__ l2_b,
    const float* __restrict__ ro_w, const float* __restrict__ ro_b,
    float* __restrict__ racc) {
  __shared__ float s_w1[64*256];
  __shared__ float s_w2t[64*256];
  __shared__ float s_b1[256];
  __shared__ float s_b2[64];
  __shared__ float s_ro[128];
  __shared__ float s_x[4][4][64];
  __shared__ float s_hm[4][4][256];
  int tid = threadIdx.x;
  for (int k = tid; k < 16384; k += 256) {
    s_w1[k] = l1_w[k];
    int j = k >> 6, l = k & 63;
    int jb = j >> 2, q = j & 3;
    s_w2t[l*256 + ((jb ^ (l & 7)) << 2) + q] = l2_w[k];
  }
  s_b1[tid] = l1_b[tid];
  if (tid < 64) s_b2[tid] = l2_b[tid];
  if (tid < 128) s_ro[tid] = ro_w[tid];
  __syncthreads();
  float rb0 = ro_b[0], rb1 = ro_b[1];
  int wid = tid >> 6, lane = tid & 63;
  int lx = lane & 7;
  int nw = gridDim.x * 4;
  const float4* w2row = (const float4*)&s_w2t[lane*256];
  for (int g = blockIdx.x*4 + wid; g < N_*ORI_/4; g += nw) {
    int r0 = g * 4;
#pragma unroll
    for (int rr = 0; rr < 4; ++rr) s_x[wid][rr][lane] = xn[(size_t)(r0+rr)*64 + lane];
    wave_sync();
    float4 b1v = *(const float4*)&s_b1[4*lane];
    float4 mm[4] = {b1v, b1v, b1v, b1v};
#pragma unroll
    for (int c4 = 0; c4 < 16; ++c4) {
      float4 xv[4];
#pragma unroll
      for (int rr = 0; rr < 4; ++rr) xv[rr] = *(const float4*)&s_x[wid][rr][c4*4];
#pragma unroll
      for (int cc = 0; cc < 4; ++cc) {
        float4 w = *(const float4*)&s_w1[(c4*4+cc)*256 + 4*lane];
#pragma unroll
        for (int rr = 0; rr < 4; ++rr) {
          float xs = (&xv[rr].x)[cc];
          mm[rr].x += xs*w.x; mm[rr].y += xs*w.y; mm[rr].z += xs*w.z; mm[rr].w += xs*w.w;
        }
      }
    }
#pragma unroll
    for (int rr = 0; rr < 4; ++rr) {
      s_hm[wid][rr][4*lane+0] = gelu_f(mm[rr].x);
      s_hm[wid][rr][4*lane+1] = gelu_f(mm[rr].y);
      s_hm[wid][rr][4*lane+2] = gelu_f(mm[rr].z);
      s_hm[wid][rr][4*lane+3] = gelu_f(mm[rr].w);
    }
    wave_sync();
    float acc[4];
#pragma unroll
    for (int rr = 0; rr < 4; ++rr) acc[rr] = s_b2[lane];
#pragma unroll 8
    for (int jb = 0; jb < 64; ++jb) {
      float4 w = w2row[jb ^ lx];
#pragma unroll
      for (int rr = 0; rr < 4; ++rr) {
        float4 hm4 = *(const float4*)&s_hm[wid][rr][jb*4];
        acc[rr] += hm4.x*w.x + hm4.y*w.y + hm4.z*w.z + hm4.w*w.w;
      }
    }
#pragma unroll
    for (int rr = 0; rr < 4; ++rr) {
      size_t idx = (size_t)(r0+rr)*64 + lane;
      float hnew = acc[rr] + h[idx];
      h[idx] = hnew;
      float v0 = wave_sum64(hnew * s_ro[lane*2+0]);
      float v1 = wave_sum64(hnew * s_ro[lane*2+1]);
      if (lane == 0) {
        racc[(r0+rr)*2+0] += v0 + rb0;
        racc[(r0+rr)*2+1] += v1 + rb1;
      }
    }
  }
}

// ---------------------------------------------------------------------------
// Final segment-sum
// ---------------------------------------------------------------------------
__global__ __launch_bounds__(256) void k_final(
    const float* __restrict__ racc, const int* __restrict__ batch,
    const float* __restrict__ g_ori, float* __restrict__ out) {
  __shared__ float s_part[32];
  __shared__ float s_ori[36];
  int tid = threadIdx.x;
  if (tid < 32) s_part[tid] = 0.f;
  if (tid < 36) s_ori[tid] = g_ori[tid];
  __syncthreads();
  const float sc = 1.0f / 36.0f;
  for (int n = blockIdx.x*256 + tid; n < N_; n += gridDim.x*256) {
    int bt = batch[n];
    float ss = 0.f, v0 = 0.f, v1 = 0.f, v2 = 0.f;
#pragma unroll
    for (int o = 0; o < 12; ++o) {
      float r0 = racc[n*24 + o*2 + 0];
      float r1 = racc[n*24 + o*2 + 1];
      ss += r0;
      v0 += r1 * s_ori[o*3+0];
      v1 += r1 * s_ori[o*3+1];
      v2 += r1 * s_ori[o*3+2];
    }
    atomicAdd(&s_part[bt], ss*sc);
    atomicAdd(&s_part[8 + bt*3 + 0], v0*sc);
    atomicAdd(&s_part[8 + bt*3 + 1], v1*sc);
    atomicAdd(&s_part[8 + bt*3 + 2], v2*sc);
  }
  __syncthreads();
  if (tid < 32) atomicAdd(&out[tid], s_part[tid]);
}

extern "C" void kernel_launch(void* const* d_in, const int* in_sizes, int n_in,
                              void* d_out, int out_size, void* d_ws, size_t ws_size,
                              hipStream_t stream) {
  const float* pos    = (const float*)d_in[0];
  const float* x      = (const float*)d_in[1];
  const int*   ei     = (const int*)d_in[2];
  const int*   batch  = (const int*)d_in[3];
  const float* sb_w1  = (const float*)d_in[4];
  const float* sb_b1  = (const float*)d_in[5];
  const float* sb_w2  = (const float*)d_in[6];
  const float* sb_b2  = (const float*)d_in[7];
  const float* fb_w1  = (const float*)d_in[8];
  const float* fb_b1  = (const float*)d_in[9];
  const float* fb_w2  = (const float*)d_in[10];
  const float* fb_b2  = (const float*)d_in[11];
  const float* emb_w  = (const float*)d_in[12];
  const float* conv_kw= (const float*)d_in[13];
  const float* fib_kw = (const float*)d_in[14];
  const float* conv_b = (const float*)d_in[15];
  const float* ln_s   = (const float*)d_in[16];
  const float* ln_b   = (const float*)d_in[17];
  const float* l1_w   = (const float*)d_in[18];
  const float* l1_b   = (const float*)d_in[19];
  const float* l2_w   = (const float*)d_in[20];
  const float* l2_b   = (const float*)d_in[21];
  const float* ro_w   = (const float*)d_in[22];
  const float* ro_b   = (const float*)d_in[23];

  float* ws_f   = (float*)d_ws;
  float* g_ori  = ws_f + OFF_ORI;
  float* g_fk   = ws_f + OFF_FK;
  float* g_h    = ws_f + OFF_H;
  float* g_xn   = ws_f + OFF_XN;                       // legacy fp32 xn
  unsigned short* g_xnb = (unsigned short*)(ws_f + OFF_XN);  // mode-1 bf16 xn
  float* g_racc = ws_f + OFF_RACC;
  int*   row_ptr= (int*)(ws_f + OFF_RP);
  int*   cursor = (int*)(ws_f + OFF_CUR);
  int*   e0s    = (int*)(ws_f + OFF_E0S);
  float4* rel4  = (float4*)(ws_f + OFF_REL);
  unsigned short* g_wp = (unsigned short*)(ws_f + OFF_WP);
  unsigned* kb_u= (unsigned*)(ws_f + OFF_KB);
  float* out_f  = (float*)d_out;

  int mode = (ws_size >= NEED_BF16) ? 1 : 2;

  (void)hipMemsetAsync(g_racc, 0, 240000*sizeof(float), stream);
  k_setup<<<3, 256, 0, stream>>>(fb_w1, fb_b1, fb_w2, fb_b2, fib_kw, g_ori, g_fk);
  k_embed<<<512, 256, 0, stream>>>(x, emb_w, g_h);

  if (mode == 1) {
    (void)hipMemsetAsync(cursor, 0, (N_+1)*sizeof(int), stream);
    k_count<<<(E_+255)/256, 256, 0, stream>>>(ei, cursor);
    k_scan<<<1, 256, 0, stream>>>(cursor, row_ptr);
    k_scatter<<<(E_+255)/256, 256, 0, stream>>>(pos, ei, cursor, e0s, rel4);
    k_sortbins<<<(N_+255)/256, 256, 0, stream>>>(row_ptr, e0s, rel4);
    k_pack<<<3, 256, 0, stream>>>(l1_w, l2_w, g_wp);
    k_basis_bf<<<(E_*ORI_)/256, 256, 0, stream>>>(rel4, sb_w1, sb_b1, sb_w2, sb_b2, g_ori, kb_u);
    for (int i = 0; i < 3; ++i) {
      k_aggr_bf<<<N_, 256, 0, stream>>>(kb_u, row_ptr, e0s, conv_kw + i*4096,
                                        g_fk + i*9216, conv_b + i*64,
                                        ln_s + i*64, ln_b + i*64, g_h, g_xnb);
      k_mlp_mfma<<<256, 512, 0, stream>>>(g_xnb, g_h,
                                          g_wp + (size_t)i*32768, g_wp + (size_t)i*32768 + 16384,
                                          l1_b + i*256, l2_b + i*64,
                                          ro_w + i*128, ro_b + i*2, g_racc);
    }
  } else {
    for (int i = 0; i < 3; ++i) {
      (void)hipMemsetAsync(g_xn, 0, 7680000*sizeof(float), stream);
      k_msg<<<1024, 256, 0, stream>>>(pos, ei, sb_w1, sb_b1, sb_w2, sb_b2,
                                      conv_kw + i*4096, g_ori, g_h, g_xn);
      k_convln<<<1024, 256, 0, stream>>>(g_xn, g_fk + i*9216, conv_b + i*64,
                                         ln_s + i*64, ln_b + i*64);
      k_mlp<<<512, 256, 0, stream>>>(g_xn, g_h, l1_w + i*16384, l1_b + i*256,
                                     l2_w + i*16384, l2_b + i*64,
                                     ro_w + i*128, ro_b + i*2, g_racc);
    }
  }
  (void)hipMemsetAsync(out_f, 0, 32*sizeof(float), stream);
  k_final<<<128, 256, 0, stream>>>(g_racc, batch, g_ori, out_f);
}